// Round 12
// baseline (3795.457 us; speedup 1.0000x reference)
//
#include <hip/hip_runtime.h>
#include <hip/hip_bf16.h>

typedef unsigned long long ull;
typedef unsigned int u32;
typedef unsigned short u16;
typedef __hip_bfloat16 bf16;
typedef __attribute__((ext_vector_type(8))) short v8s;
typedef __attribute__((ext_vector_type(4))) float v4f;
typedef __attribute__((ext_vector_type(2))) ull v2u;

#define NN 50000
#define DD 300
#define PD 320
#define EE (NN*6)

__device__ __forceinline__ u16 f2bf(float f) {
    u32 u = __float_as_uint(f);
    u32 r = u + 0x7FFFu + ((u >> 16) & 1u);
    return (u16)(r >> 16);
}
__device__ __forceinline__ u32 cvtpk(float lo, float hi) {
    u32 r;
    asm("v_cvt_pk_bf16_f32 %0, %1, %2" : "=v"(r) : "v"(lo), "v"(hi));
    return r;
}
__device__ __forceinline__ float lo16(u32 u) { return __uint_as_float(u << 16); }
__device__ __forceinline__ float hi16(u32 u) { return __uint_as_float(u & 0xffff0000u); }

__device__ __forceinline__ u32 sub2bf(u32 a, u32 b) {
    return cvtpk(lo16(a) - lo16(b), hi16(a) - hi16(b));
}
__device__ __forceinline__ ull sub4bf(ull a, ull b) {
    u32 l = sub2bf((u32)a, (u32)b);
    u32 h = sub2bf((u32)(a >> 32), (u32)(b >> 32));
    return (ull)l | ((ull)h << 32);
}

// async global->LDS, 16 B/lane: lane's data lands at lds_base + lane*16.
__device__ __forceinline__ void gl16(const void* g, void* l) {
    __builtin_amdgcn_global_load_lds(
        (const __attribute__((address_space(1))) u32*)g,
        (__attribute__((address_space(3))) u32*)l, 16, 0, 0);
}

enum { E_BIAS = 0, E_MPG = 1 };
enum { O_F32 = 1, O_BF16 = 2 };

// C[M,320] = sum_seg A_seg[M,320] @ BT_seg (+bias) (+epi). BT bf16 [col][320].
// 32-row tile, 256 threads (4 waves x 80-col quarters), acc[2][5], 20KB LDS
// -> 8 blocks/CU residency (vs 4 at 64-row): more TLP phase overlap.
// E_BIAS: linear gl16 staging (involutory source chunk swizzle, linear dest).
// E_MPG : register-staged A0[src[row]] - A1[row^1], swizzled ds_write;
//         writer does relu(x + val). grid.y slices BT/bias/Cb.
template<int EPI, int OUTM, int NSEG>
__global__ __launch_bounds__(256, 8)
void gemm_mfma(const bf16* __restrict__ A0, const bf16* __restrict__ A1,
               const bf16* __restrict__ A2, const bf16* __restrict__ A3,
               const bf16* __restrict__ A4,
               const int* __restrict__ srcidx,
               const bf16* __restrict__ BT, const float* __restrict__ bias0,
               const bf16* __restrict__ xepi,
               float* __restrict__ Cf, bf16* __restrict__ Cb0,
               int M, long ycb)
{
    __shared__ __align__(16) char Als[32 * 640];
    const int tid = threadIdx.x;
    const int wave = tid >> 6, lane = tid & 63;
    const int l15 = lane & 15, l4 = lane >> 4;
    const int wc = wave;                      // 4 waves = 4 col-quarters
    const int rowBase = blockIdx.x * 32;
    const int gy = blockIdx.y;
    BT += (long)gy * 102400;
    if (bias0) bias0 += (long)gy * 320;
    if (Cb0) Cb0 += (long)gy * ycb;

    v4f acc[2][5];
    const v4f vzero = {0.f, 0.f, 0.f, 0.f};
    #pragma unroll
    for (int mt = 0; mt < 2; ++mt)
        #pragma unroll
        for (int nt = 0; nt < 5; ++nt) acc[mt][nt] = vzero;

    for (int seg = 0; seg < NSEG; ++seg) {
        const bf16* As = (seg == 0) ? A0 : (seg == 1 ? A1 : (seg == 2 ? A2 :
                         (seg == 3 ? A3 : A4)));
        if (seg) __syncthreads();
        #pragma unroll
        for (int s = 0; s < 5; ++s) {
            int c = tid + 256 * s;
            int r = c / 40, ch = c - r * 40;
            int grow = rowBase + r;
            grow = (grow < M) ? grow : (M - 1);      // clamp; junk discarded
            if (EPI == E_MPG) {
                int sr = srcidx[grow];
                v2u a = *(const v2u*)(A0 + (long)sr * PD + ch * 8);
                v2u b = *(const v2u*)(A1 + (long)(grow ^ 1) * PD + ch * 8);
                v2u v;
                v[0] = sub4bf(a[0], b[0]);
                v[1] = sub4bf(a[1], b[1]);
                *(v2u*)(Als + ((c * 16) ^ ((r & 7) << 4))) = v;
            } else {
                int chs = ch ^ (r & 7);               // involutory chunk swizzle
                gl16(As + (long)grow * PD + chs * 8,
                     Als + (wave * 64 + 256 * s) * 16);  // wave-uniform base
            }
        }
        __syncthreads();

        const bf16* BTs = BT + (long)seg * 102400;
        #pragma unroll
        for (int ks = 0; ks < 10; ++ks) {
            v8s af[2];
            #pragma unroll
            for (int mt = 0; mt < 2; ++mt) {
                int rowL = mt * 16 + l15;
                af[mt] = *(const v8s*)(Als +
                    ((rowL * 640 + ks * 64 + l4 * 16) ^ ((rowL & 7) << 4)));
            }
            #pragma unroll
            for (int nt = 0; nt < 5; ++nt) {
                int col = wc * 80 + nt * 16 + l15;
                v8s bfr = *(const v8s*)(BTs + (long)col * PD + ks * 32 + l4 * 8);
                #pragma unroll
                for (int mt = 0; mt < 2; ++mt)
                    acc[mt][nt] = __builtin_amdgcn_mfma_f32_16x16x32_bf16(
                        af[mt], bfr, acc[mt][nt], 0, 0, 0);
            }
        }
    }

    // ---- phase A: acc (+bias) -> LDS bf16 tile, swizzled ----
    __syncthreads();
    #pragma unroll
    for (int nt = 0; nt < 5; ++nt) {
        int col = wc * 80 + nt * 16 + l15;
        float bvv = bias0 ? bias0[col] : 0.f;
        #pragma unroll
        for (int mt = 0; mt < 2; ++mt) {
            #pragma unroll
            for (int rr = 0; rr < 4; ++rr) {
                int rowL = mt * 16 + l4 * 4 + rr;
                *(u16*)(Als + ((rowL * 640 + col * 2) ^ (((rowL >> 2) & 7) << 4)))
                    = f2bf(acc[mt][nt][rr] + bvv);
            }
        }
    }
    __syncthreads();

    // ---- phase B: writer ----
    #pragma unroll
    for (int s = 0; s < 5; ++s) {
        int c = tid + 256 * s;
        int r = c / 40, ch = c - r * 40;
        int grow = rowBase + r;
        if (grow >= M) continue;
        v2u val = *(const v2u*)(Als + ((c * 16) ^ (((r >> 2) & 7) << 4)));
        if (EPI == E_MPG) {
            v2u xv = *(const v2u*)(xepi + (long)grow * PD + ch * 8);
            #pragma unroll
            for (int w = 0; w < 2; ++w) {
                u32 a0 = (u32)val[w], a1 = (u32)(val[w] >> 32);
                u32 x0 = (u32)xv[w],  x1 = (u32)(xv[w] >> 32);
                u32 r0 = cvtpk(fmaxf(lo16(a0) + lo16(x0), 0.f),
                               fmaxf(hi16(a0) + hi16(x0), 0.f));
                u32 r1 = cvtpk(fmaxf(lo16(a1) + lo16(x1), 0.f),
                               fmaxf(hi16(a1) + hi16(x1), 0.f));
                val[w] = (ull)r0 | ((ull)r1 << 32);
            }
        }
        if (OUTM & O_BF16)
            *(v2u*)(Cb0 + (long)grow * PD + ch * 8) = val;
        if (OUTM & O_F32) {
            int col0 = ch * 8;
            if (col0 < DD) {
                u32 a0 = (u32)val[0], a1 = (u32)(val[0] >> 32);
                float4 lo = {lo16(a0), hi16(a0), lo16(a1), hi16(a1)};
                *(float4*)(Cf + (long)grow * DD + col0) = lo;
                if (col0 + 4 < DD) {
                    u32 b0 = (u32)val[1], b1 = (u32)(val[1] >> 32);
                    float4 hi4 = {lo16(b0), hi16(b0), lo16(b1), hi16(b1)};
                    *(float4*)(Cf + (long)grow * DD + col0 + 4) = hi4;
                }
            }
        }
    }
}

// ---- scoreU: s[h,d] = scale*(h_d . G_h[n]); softmax; U_h = sum_d a*h_d ----
__global__ __launch_bounds__(256)
void scoreU_k(const bf16* __restrict__ G0, const bf16* __restrict__ G1,
              const bf16* __restrict__ G2, const bf16* __restrict__ G3,
              const bf16* __restrict__ h, const int* __restrict__ nbr,
              bf16* __restrict__ U0, bf16* __restrict__ U1,
              bf16* __restrict__ U2, bf16* __restrict__ U3)
{
    int wave = threadIdx.x >> 6, lane = threadIdx.x & 63;
    int n = blockIdx.x * 4 + wave;
    if (n >= NN) return;
    int eid[6];
    #pragma unroll
    for (int d = 0; d < 6; ++d) eid[d] = nbr[n * 6 + d];

    bool act = lane < 40;
    int cl = act ? lane : 0;
    long go = (long)n * PD + cl * 8;

    float g[4][8];
    #pragma unroll
    for (int hh = 0; hh < 4; ++hh) {
        const bf16* Gp = (hh == 0) ? G0 : (hh == 1) ? G1 : (hh == 2) ? G2 : G3;
        v2u gv = *(const v2u*)(Gp + go);
        u32 w0 = (u32)gv[0], w1 = (u32)(gv[0] >> 32);
        u32 w2 = (u32)gv[1], w3 = (u32)(gv[1] >> 32);
        g[hh][0] = lo16(w0); g[hh][1] = hi16(w0);
        g[hh][2] = lo16(w1); g[hh][3] = hi16(w1);
        g[hh][4] = lo16(w2); g[hh][5] = hi16(w2);
        g[hh][6] = lo16(w3); g[hh][7] = hi16(w3);
        if (!act)
            #pragma unroll
            for (int i = 0; i < 8; ++i) g[hh][i] = 0.f;
    }
    v2u hp[6];
    #pragma unroll
    for (int d = 0; d < 6; ++d)
        hp[d] = *(const v2u*)(h + (long)eid[d] * PD + cl * 8);

    float s0[6], s1[6], s2[6], s3[6];
    #pragma unroll
    for (int d = 0; d < 6; ++d) {
        u32 w0 = (u32)hp[d][0], w1 = (u32)(hp[d][0] >> 32);
        u32 w2 = (u32)hp[d][1], w3 = (u32)(hp[d][1] >> 32);
        float hf[8] = {lo16(w0), hi16(w0), lo16(w1), hi16(w1),
                       lo16(w2), hi16(w2), lo16(w3), hi16(w3)};
        float p0 = 0, p1 = 0, p2 = 0, p3 = 0;
        #pragma unroll
        for (int i = 0; i < 8; ++i) {
            p0 += g[0][i] * hf[i];
            p1 += g[1][i] * hf[i];
            p2 += g[2][i] * hf[i];
            p3 += g[3][i] * hf[i];
        }
        #pragma unroll
        for (int off = 32; off; off >>= 1) {
            p0 += __shfl_xor(p0, off);
            p1 += __shfl_xor(p1, off);
            p2 += __shfl_xor(p2, off);
            p3 += __shfl_xor(p3, off);
        }
        s0[d] = p0; s1[d] = p1; s2[d] = p2; s3[d] = p3;
    }

    const float scale = 0.1154700538379252f; // 1/sqrt(75)
    float at[4][6];
    {
        float m0 = -1e30f, m1 = -1e30f, m2 = -1e30f, m3 = -1e30f;
        #pragma unroll
        for (int d = 0; d < 6; ++d) {
            s0[d] *= scale; s1[d] *= scale; s2[d] *= scale; s3[d] *= scale;
            m0 = fmaxf(m0, s0[d]); m1 = fmaxf(m1, s1[d]);
            m2 = fmaxf(m2, s2[d]); m3 = fmaxf(m3, s3[d]);
        }
        float t0 = 0, t1 = 0, t2 = 0, t3 = 0;
        #pragma unroll
        for (int d = 0; d < 6; ++d) {
            at[0][d] = expf(s0[d] - m0); t0 += at[0][d];
            at[1][d] = expf(s1[d] - m1); t1 += at[1][d];
            at[2][d] = expf(s2[d] - m2); t2 += at[2][d];
            at[3][d] = expf(s3[d] - m3); t3 += at[3][d];
        }
        t0 = 1.f / t0; t1 = 1.f / t1; t2 = 1.f / t2; t3 = 1.f / t3;
        #pragma unroll
        for (int d = 0; d < 6; ++d) {
            at[0][d] *= t0; at[1][d] *= t1; at[2][d] *= t2; at[3][d] *= t3;
        }
    }

    float u[4][8];
    #pragma unroll
    for (int hh = 0; hh < 4; ++hh)
        #pragma unroll
        for (int i = 0; i < 8; ++i) u[hh][i] = 0.f;
    #pragma unroll
    for (int d = 0; d < 6; ++d) {
        u32 w0 = (u32)hp[d][0], w1 = (u32)(hp[d][0] >> 32);
        u32 w2 = (u32)hp[d][1], w3 = (u32)(hp[d][1] >> 32);
        float hf[8] = {lo16(w0), hi16(w0), lo16(w1), hi16(w1),
                       lo16(w2), hi16(w2), lo16(w3), hi16(w3)};
        #pragma unroll
        for (int i = 0; i < 8; ++i) {
            u[0][i] += at[0][d] * hf[i];
            u[1][i] += at[1][d] * hf[i];
            u[2][i] += at[2][d] * hf[i];
            u[3][i] += at[3][d] * hf[i];
        }
    }
    if (act) {
        #pragma unroll
        for (int hh = 0; hh < 4; ++hh) {
            bf16* Up = (hh == 0) ? U0 : (hh == 1) ? U1 : (hh == 2) ? U2 : U3;
            v2u r;
            r[0] = (ull)cvtpk(u[hh][0], u[hh][1]) |
                   ((ull)cvtpk(u[hh][2], u[hh][3]) << 32);
            r[1] = (ull)cvtpk(u[hh][4], u[hh][5]) |
                   ((ull)cvtpk(u[hh][6], u[hh][7]) << 32);
            *(v2u*)(Up + go) = r;
        }
    }
}

// ---- mail from f32 h_final: mail[n] = sum_d h[nbr[n,d]] -> bf16 padded ----
__global__ __launch_bounds__(256)
void mailf_k(const float* __restrict__ h, const int* __restrict__ nbr,
             bf16* __restrict__ mail)
{
    int idx = blockIdx.x * 256 + threadIdx.x;
    if (idx >= NN * 80) return;
    int n = idx / 80, c4 = idx - n * 80;
    float4 s = {0.f, 0.f, 0.f, 0.f};
    if (c4 < 75) {
        const int* e = nbr + n * 6;
        #pragma unroll
        for (int d = 0; d < 6; ++d) {
            float4 v = *(const float4*)(h + (long)e[d] * DD + c4 * 4);
            s.x += v.x; s.y += v.y; s.z += v.z; s.w += v.w;
        }
    }
    ull r = (ull)cvtpk(s.x, s.y) | ((ull)cvtpk(s.z, s.w) << 32);
    *(ull*)(mail + (long)n * PD + c4 * 4) = r;
}

// ---- f32[rows,300] -> bf16[rows,320] padded ----
__global__ __launch_bounds__(256)
void conv_k(const float* __restrict__ in, bf16* __restrict__ out, int rows)
{
    long idx = (long)blockIdx.x * 256 + threadIdx.x;
    if (idx >= (long)rows * 40) return;
    int r = (int)(idx / 40), ch = (int)(idx - (long)r * 40);
    int c4 = ch * 2;
    float4 a = {0, 0, 0, 0}, b = {0, 0, 0, 0};
    if (c4 < 75)     a = *(const float4*)(in + (long)r * DD + c4 * 4);
    if (c4 + 1 < 75) b = *(const float4*)(in + (long)r * DD + c4 * 4 + 4);
    v2u v;
    v[0] = (ull)cvtpk(a.x, a.y) | ((ull)cvtpk(a.z, a.w) << 32);
    v[1] = (ull)cvtpk(b.x, b.y) | ((ull)cvtpk(b.z, b.w) << 32);
    *(v2u*)(out + (long)r * PD + ch * 8) = v;
}

// ---- weight transpose+convert: BT[c][k] = W[k][c], 320x320 bf16 pad ----
__global__ __launch_bounds__(256)
void tw_k(const float* __restrict__ W, bf16* __restrict__ BT)
{
    int idx = blockIdx.x * 256 + threadIdx.x;
    if (idx >= 320 * 320) return;
    int nn = idx / 320, kk = idx - nn * 320;
    u16 v = 0;
    if (nn < DD && kk < DD) v = f2bf(W[kk * DD + nn]);
    ((u16*)BT)[idx] = v;
}

// ---- f32 transpose: WT[c][r] = W[r][c], [300,300] -> [320,320] pad ----
__global__ __launch_bounds__(256)
void twf_k(const float* __restrict__ W, float* __restrict__ WT)
{
    __shared__ float t[32][33];
    int bx = blockIdx.x % 10, by = blockIdx.x / 10;
    int r0 = by * 32, c0 = bx * 32;
    int tx = threadIdx.x & 31, ty = threadIdx.x >> 5;
    #pragma unroll
    for (int i = 0; i < 4; ++i) {
        int r = r0 + ty + i * 8, c = c0 + tx;
        t[ty + i * 8][tx] = (r < DD && c < DD) ? W[r * DD + c] : 0.f;
    }
    __syncthreads();
    #pragma unroll
    for (int i = 0; i < 4; ++i)
        WT[(c0 + ty + i * 8) * 320 + r0 + tx] = t[tx][ty + i * 8];
}

// ---- composed QK (coalesced): slab[c][k] = sum_j WqT[jb+j][k]*Wk[ci][jb+j] ----
__global__ __launch_bounds__(256)
void wqk_k(const float* __restrict__ WqT, const float* __restrict__ Wk,
           bf16* __restrict__ slab)
{
    int idx = blockIdx.x * 256 + threadIdx.x;
    if (idx >= 1280 * 320) return;
    int c = idx / 320, k = idx - c * 320;
    int hh = c / 320;
    int ci = c - hh * 320;
    float v = 0.f;
    if (ci < DD && k < DD) {
        int jb = hh * 75;
        for (int j = 0; j < 75; ++j)
            v += WqT[(jb + j) * 320 + k] * Wk[ci * DD + jb + j];
    }
    ((u16*)slab)[idx] = f2bf(v);
}

// ---- composed V-O (coalesced): 5 slots: s<4: Wv_h@Wo_h ; s=4: Wv@Wo ----
__global__ __launch_bounds__(256)
void wcomp_k(const float* __restrict__ WvT, const float* __restrict__ Wo,
             bf16* __restrict__ slab)
{
    int idx = blockIdx.x * 256 + threadIdx.x;
    if (idx >= 5 * 320 * 320) return;
    int s = idx / 102400, rem = idx - s * 102400;
    int c = rem / 320, k = rem - c * 320;
    float v = 0.f;
    if (c < DD && k < DD) {
        int jb = (s < 4) ? s * 75 : 0;
        int jn = (s < 4) ? 75 : 300;
        for (int j = 0; j < jn; ++j)
            v += WvT[(jb + j) * 320 + k] * Wo[(jb + j) * DD + c];
    }
    ((u16*)slab)[idx] = f2bf(v);
}

// ---- padded bias vectors (8 x 320 f32) ----
__global__ void bias_k(const float* __restrict__ WkT, const float* __restrict__ Wo,
                       const float* __restrict__ bq, const float* __restrict__ bv,
                       const float* __restrict__ bo, const float* __restrict__ bmp,
                       const float* __restrict__ blast, float* __restrict__ outb)
{
    int a = blockIdx.x, i = threadIdx.x; // 8 x 320
    float v = 0.f;
    if (i < DD) {
        if (a < 4) {
            for (int j = 0; j < 75; ++j)
                v += bq[a * 75 + j] * WkT[(a * 75 + j) * 320 + i];
        } else if (a == 4) {
            for (int j = 0; j < DD; ++j) v += bv[j] * Wo[j * DD + i];
            v += bo[i];
        } else if (a == 5) v = bmp[i];
        else if (a == 6) v = bmp[DD + i];
        else v = blast[i];
    }
    outb[a * 320 + i] = v;
}

extern "C" void kernel_launch(void* const* d_in, const int* in_sizes, int n_in,
                              void* d_out, int out_size, void* d_ws, size_t ws_size,
                              hipStream_t stream)
{
    const float* f     = (const float*)d_in[0];
    const float* x     = (const float*)d_in[1];
    const float* Wq    = (const float*)d_in[2];
    const float* bq    = (const float*)d_in[3];
    const float* Wk    = (const float*)d_in[4];
    const float* bv    = (const float*)d_in[7];
    const float* Wv    = (const float*)d_in[6];
    const float* Wo    = (const float*)d_in[8];
    const float* bo    = (const float*)d_in[9];
    const float* Wmp   = (const float*)d_in[10];
    const float* bmp   = (const float*)d_in[11];
    const float* Wlast = (const float*)d_in[12];
    const float* blast = (const float*)d_in[13];
    const int*   src   = (const int*)d_in[14];
    const int*   nbr   = (const int*)d_in[16];

    float* out     = (float*)d_out;
    float* f_final = out;
    float* h_final = out + (long)NN * DD;

    // ws layout (ends ~772.7 MB; proven-safe bound ~901.8 MB):
    char* ws = (char*)d_ws;
    bf16* xb  = (bf16*)(ws);                   // [E,320] 192e6
    bf16* h1b = (bf16*)(ws + 192000000LL);     // [E,320]
    bf16* fb  = (bf16*)(ws + 576000000LL);     // [N,320] 32e6
    bf16* G0  = (bf16*)(ws + 608000000LL);     // [N,320] x4 (alias U, mail)
    bf16* G1  = (bf16*)(ws + 640000000LL);
    bf16* G2  = (bf16*)(ws + 672000000LL);
    bf16* G3  = (bf16*)(ws + 704000000LL);
    bf16* FHb = (bf16*)(ws + 736000000LL);     // [N,320]
    bf16* WT  = (bf16*)(ws + 768000000LL);     // 14 slots x 204800 B
    float* BIAS = (float*)(ws + 771300000LL);  // 8 x 320 f32
    float* WqT  = (float*)(ws + 771400000LL);  // 320x320 f32 each
    float* WkT  = (float*)(ws + 771850000LL);
    float* WvT  = (float*)(ws + 772300000LL);
    auto slot = [&](int i) { return WT + (long)i * 320 * 320; };
    // slots: 0-3 qk heads | 4-8 fh(comp0..3,vo) | 9 mp0 | 10 mp1 | 11-13 last
    bf16* qk   = slot(0);
    bf16* fh5  = slot(4);
    float* g0p = BIAS;
    float* b2p = BIAS + 1280;
    float* bm0p = BIAS + 1600;  float* bm1p = BIAS + 1920;
    float* blp = BIAS + 2240;
    bf16* MLb = G0;

    dim3 blk(256);
    const int gN = (NN + 31) / 32;   // 1563
    const int gE = (EE + 31) / 32;   // 9375

    conv_k<<<(int)(((long)EE * 40 + 255) / 256), blk, 0, stream>>>(x, xb, EE);
    conv_k<<<(int)(((long)NN * 40 + 255) / 256), blk, 0, stream>>>(f, fb, NN);
    twf_k<<<100, blk, 0, stream>>>(Wq, WqT);
    twf_k<<<100, blk, 0, stream>>>(Wk, WkT);
    twf_k<<<100, blk, 0, stream>>>(Wv, WvT);
    wqk_k<<<1600, blk, 0, stream>>>(WqT, Wk, qk);
    wcomp_k<<<2000, blk, 0, stream>>>(WvT, Wo, fh5);
    tw_k<<<400, blk, 0, stream>>>(Wmp, slot(9));
    tw_k<<<400, blk, 0, stream>>>(Wmp + 90000, slot(10));
    tw_k<<<400, blk, 0, stream>>>(Wlast, slot(11));
    tw_k<<<400, blk, 0, stream>>>(Wlast + 90000, slot(12));
    tw_k<<<400, blk, 0, stream>>>(Wlast + 180000, slot(13));
    bias_k<<<8, 320, 0, stream>>>(WkT, Wo, bq, bv, bo, bmp, blast, BIAS);

    for (int it = 0; it < 2; ++it) {
        const bf16* hb  = it ? h1b : xb;
        const bf16* fhb = it ? FHb : fb;
        const bf16* mpW = it ? slot(10) : slot(9);
        // G_h = f_h @ Wqk_h + g_h   (grid.y = 4 heads)
        gemm_mfma<E_BIAS, O_BF16, 1><<<dim3(gN, 4), blk, 0, stream>>>(
            fhb, nullptr, nullptr, nullptr, nullptr, nullptr,
            qk, g0p, nullptr, nullptr, G0, NN, 16000000);
        // scores + softmax + U_h (U aliases G)
        scoreU_k<<<(NN + 3) / 4, blk, 0, stream>>>(G0, G1, G2, G3, hb, nbr,
                                                   G0, G1, G2, G3);
        // f_h_new = sum_h U_h@Wcomp_h + f_h@Wvo + b2
        gemm_mfma<E_BIAS, O_BF16, 5><<<gN, blk, 0, stream>>>(
            G0, G1, G2, G3, fhb, nullptr, fh5, b2p, nullptr,
            nullptr, FHb, NN, 0);
        // h_new = relu(x + (f_h[src]-h[rev])@Wmp + bmp)  (register-staged gather)
        if (it == 0) {
            gemm_mfma<E_MPG, O_BF16, 1><<<gE, blk, 0, stream>>>(
                FHb, hb, nullptr, nullptr, nullptr, src,
                mpW, bm0p, xb, nullptr, h1b, EE, 0);
        } else {
            gemm_mfma<E_MPG, O_F32, 1><<<gE, blk, 0, stream>>>(
                FHb, hb, nullptr, nullptr, nullptr, src,
                mpW, bm1p, xb, h_final, nullptr, EE, 0);
        }
    }

    mailf_k<<<(NN * 80 + 255) / 256, blk, 0, stream>>>(h_final, nbr, MLb);
    gemm_mfma<E_BIAS, O_F32, 3><<<gN, blk, 0, stream>>>(
        MLb, FHb, fb, nullptr, nullptr, nullptr, slot(11), blp,
        nullptr, f_final, nullptr, NN, 0);
}

// Round 13
// 2217.254 us; speedup vs baseline: 1.7118x; 1.7118x over previous
//
#include <hip/hip_runtime.h>
#include <hip/hip_bf16.h>

typedef unsigned long long ull;
typedef unsigned int u32;
typedef unsigned short u16;
typedef __hip_bfloat16 bf16;
typedef __attribute__((ext_vector_type(8))) short v8s;
typedef __attribute__((ext_vector_type(4))) float v4f;
typedef __attribute__((ext_vector_type(2))) ull v2u;

#define NN 50000
#define DD 300
#define PD 320
#define EE (NN*6)

__device__ __forceinline__ u16 f2bf(float f) {
    u32 u = __float_as_uint(f);
    u32 r = u + 0x7FFFu + ((u >> 16) & 1u);
    return (u16)(r >> 16);
}
__device__ __forceinline__ u32 cvtpk(float lo, float hi) {
    u32 r;
    asm("v_cvt_pk_bf16_f32 %0, %1, %2" : "=v"(r) : "v"(lo), "v"(hi));
    return r;
}
__device__ __forceinline__ float lo16(u32 u) { return __uint_as_float(u << 16); }
__device__ __forceinline__ float hi16(u32 u) { return __uint_as_float(u & 0xffff0000u); }

__device__ __forceinline__ u32 sub2bf(u32 a, u32 b) {
    return cvtpk(lo16(a) - lo16(b), hi16(a) - hi16(b));
}
__device__ __forceinline__ ull sub4bf(ull a, ull b) {
    u32 l = sub2bf((u32)a, (u32)b);
    u32 h = sub2bf((u32)(a >> 32), (u32)(b >> 32));
    return (ull)l | ((ull)h << 32);
}

// async global->LDS, 16 B/lane: lane's data lands at lds_base + lane*16.
__device__ __forceinline__ void gl16(const void* g, void* l) {
    __builtin_amdgcn_global_load_lds(
        (const __attribute__((address_space(1))) u32*)g,
        (__attribute__((address_space(3))) u32*)l, 16, 0, 0);
}

enum { E_BIAS = 0, E_MPG = 1, E_LAST = 2 };
enum { O_F32 = 1, O_BF16 = 2 };

// C[M,320] = sum_seg A_seg[M,320] @ BT_seg (+bias) (+epi). BT bf16 [col][320].
// 8 waves (2 row-halves x 4 col-quarters), acc[2][5], 64 rows/block, 40KB LDS.
// E_BIAS: linear gl16 staging (involutory source chunk swizzle, linear dest).
// E_MPG : register-staged A0[src[row]] - A1[row^1], swizzled ds_write;
//         writer does relu(x + val).
// E_LAST: seg0 staging = gather-sum of 6 f32 HF rows via nbrp (fused mail);
//         seg1/seg2 = linear gl16. grid.y slices BT/bias/Cb.
template<int EPI, int OUTM, int NSEG>
__global__ __launch_bounds__(512, 4)
void gemm_mfma(const bf16* __restrict__ A0, const bf16* __restrict__ A1,
               const bf16* __restrict__ A2, const bf16* __restrict__ A3,
               const bf16* __restrict__ A4,
               const int* __restrict__ srcidx,
               const float* __restrict__ HF, const int* __restrict__ nbrp,
               const bf16* __restrict__ BT, const float* __restrict__ bias0,
               const bf16* __restrict__ xepi,
               float* __restrict__ Cf, bf16* __restrict__ Cb0,
               int M, long ycb)
{
    __shared__ __align__(16) char Als[64 * 640];
    const int tid = threadIdx.x;
    const int wave = tid >> 6, lane = tid & 63;
    const int l15 = lane & 15, l4 = lane >> 4;
    const int wr = wave >> 2, wc = wave & 3;
    const int rowBase = blockIdx.x * 64;
    const int gy = blockIdx.y;
    BT += (long)gy * 102400;
    if (bias0) bias0 += (long)gy * 320;
    if (Cb0) Cb0 += (long)gy * ycb;

    v4f acc[2][5];
    const v4f vzero = {0.f, 0.f, 0.f, 0.f};
    #pragma unroll
    for (int mt = 0; mt < 2; ++mt)
        #pragma unroll
        for (int nt = 0; nt < 5; ++nt) acc[mt][nt] = vzero;

    for (int seg = 0; seg < NSEG; ++seg) {
        const bf16* As = (seg == 0) ? A0 : (seg == 1 ? A1 : (seg == 2 ? A2 :
                         (seg == 3 ? A3 : A4)));
        if (seg) __syncthreads();
        #pragma unroll
        for (int s = 0; s < 5; ++s) {
            int c = tid + 512 * s;
            int r = c / 40, ch = c - r * 40;
            int grow = rowBase + r;
            grow = (grow < M) ? grow : (M - 1);      // clamp; junk discarded
            if (EPI == E_MPG) {
                int sr = srcidx[grow];
                v2u a = *(const v2u*)(A0 + (long)sr * PD + ch * 8);
                v2u b = *(const v2u*)(A1 + (long)(grow ^ 1) * PD + ch * 8);
                v2u v;
                v[0] = sub4bf(a[0], b[0]);
                v[1] = sub4bf(a[1], b[1]);
                *(v2u*)(Als + ((c * 16) ^ ((r & 7) << 4))) = v;
            } else if (EPI == E_LAST && seg == 0) {
                // fused mail: sum 6 gathered f32 rows -> bf16 chunk
                const int* e = nbrp + grow * 6;
                int c8 = ch * 8;
                float s0 = 0, s1 = 0, s2 = 0, s3 = 0,
                      s4 = 0, s5 = 0, s6 = 0, s7 = 0;
                #pragma unroll
                for (int d = 0; d < 6; ++d) {
                    const float* hr = HF + (long)e[d] * DD + c8;
                    if (c8 < DD) {
                        float4 a = *(const float4*)hr;
                        s0 += a.x; s1 += a.y; s2 += a.z; s3 += a.w;
                    }
                    if (c8 + 4 < DD) {
                        float4 b = *(const float4*)(hr + 4);
                        s4 += b.x; s5 += b.y; s6 += b.z; s7 += b.w;
                    }
                }
                v2u v;
                v[0] = (ull)cvtpk(s0, s1) | ((ull)cvtpk(s2, s3) << 32);
                v[1] = (ull)cvtpk(s4, s5) | ((ull)cvtpk(s6, s7) << 32);
                *(v2u*)(Als + ((c * 16) ^ ((r & 7) << 4))) = v;
            } else {
                int chs = ch ^ (r & 7);               // involutory chunk swizzle
                gl16(As + (long)grow * PD + chs * 8,
                     Als + (wave * 64 + 512 * s) * 16);  // wave-uniform base
            }
        }
        __syncthreads();

        const bf16* BTs = BT + (long)seg * 102400;
        #pragma unroll
        for (int ks = 0; ks < 10; ++ks) {
            v8s af[2];
            #pragma unroll
            for (int mt = 0; mt < 2; ++mt) {
                int rowL = wr * 32 + mt * 16 + l15;
                af[mt] = *(const v8s*)(Als +
                    ((rowL * 640 + ks * 64 + l4 * 16) ^ ((rowL & 7) << 4)));
            }
            #pragma unroll
            for (int nt = 0; nt < 5; ++nt) {
                int col = wc * 80 + nt * 16 + l15;
                v8s bfr = *(const v8s*)(BTs + (long)col * PD + ks * 32 + l4 * 8);
                #pragma unroll
                for (int mt = 0; mt < 2; ++mt)
                    acc[mt][nt] = __builtin_amdgcn_mfma_f32_16x16x32_bf16(
                        af[mt], bfr, acc[mt][nt], 0, 0, 0);
            }
        }
    }

    // ---- phase A: acc (+bias) -> LDS bf16 tile, swizzled ----
    __syncthreads();
    #pragma unroll
    for (int nt = 0; nt < 5; ++nt) {
        int col = wc * 80 + nt * 16 + l15;
        float bvv = bias0 ? bias0[col] : 0.f;
        #pragma unroll
        for (int mt = 0; mt < 2; ++mt) {
            #pragma unroll
            for (int rr = 0; rr < 4; ++rr) {
                int rowL = wr * 32 + mt * 16 + l4 * 4 + rr;
                *(u16*)(Als + ((rowL * 640 + col * 2) ^ (((rowL >> 2) & 7) << 4)))
                    = f2bf(acc[mt][nt][rr] + bvv);
            }
        }
    }
    __syncthreads();

    // ---- phase B: writer ----
    #pragma unroll
    for (int s = 0; s < 5; ++s) {
        int c = tid + 512 * s;
        int r = c / 40, ch = c - r * 40;
        int grow = rowBase + r;
        if (grow >= M) continue;
        v2u val = *(const v2u*)(Als + ((c * 16) ^ (((r >> 2) & 7) << 4)));
        if (EPI == E_MPG) {
            v2u xv = *(const v2u*)(xepi + (long)grow * PD + ch * 8);
            #pragma unroll
            for (int w = 0; w < 2; ++w) {
                u32 a0 = (u32)val[w], a1 = (u32)(val[w] >> 32);
                u32 x0 = (u32)xv[w],  x1 = (u32)(xv[w] >> 32);
                u32 r0 = cvtpk(fmaxf(lo16(a0) + lo16(x0), 0.f),
                               fmaxf(hi16(a0) + hi16(x0), 0.f));
                u32 r1 = cvtpk(fmaxf(lo16(a1) + lo16(x1), 0.f),
                               fmaxf(hi16(a1) + hi16(x1), 0.f));
                val[w] = (ull)r0 | ((ull)r1 << 32);
            }
        }
        if (OUTM & O_BF16)
            *(v2u*)(Cb0 + (long)grow * PD + ch * 8) = val;
        if (OUTM & O_F32) {
            int col0 = ch * 8;
            if (col0 < DD) {
                u32 a0 = (u32)val[0], a1 = (u32)(val[0] >> 32);
                float4 lo = {lo16(a0), hi16(a0), lo16(a1), hi16(a1)};
                *(float4*)(Cf + (long)grow * DD + col0) = lo;
                if (col0 + 4 < DD) {
                    u32 b0 = (u32)val[1], b1 = (u32)(val[1] >> 32);
                    float4 hi4 = {lo16(b0), hi16(b0), lo16(b1), hi16(b1)};
                    *(float4*)(Cf + (long)grow * DD + col0 + 4) = hi4;
                }
            }
        }
    }
}

// ---- scoreU: s[h,d] = scale*(h_d . G_h[n]); softmax; U_h = sum_d a*h_d ----
__global__ __launch_bounds__(256)
void scoreU_k(const bf16* __restrict__ G0, const bf16* __restrict__ G1,
              const bf16* __restrict__ G2, const bf16* __restrict__ G3,
              const bf16* __restrict__ h, const int* __restrict__ nbr,
              bf16* __restrict__ U0, bf16* __restrict__ U1,
              bf16* __restrict__ U2, bf16* __restrict__ U3)
{
    int wave = threadIdx.x >> 6, lane = threadIdx.x & 63;
    int n = blockIdx.x * 4 + wave;
    if (n >= NN) return;
    int eid[6];
    #pragma unroll
    for (int d = 0; d < 6; ++d) eid[d] = nbr[n * 6 + d];

    bool act = lane < 40;
    int cl = act ? lane : 0;
    long go = (long)n * PD + cl * 8;

    float g[4][8];
    #pragma unroll
    for (int hh = 0; hh < 4; ++hh) {
        const bf16* Gp = (hh == 0) ? G0 : (hh == 1) ? G1 : (hh == 2) ? G2 : G3;
        v2u gv = *(const v2u*)(Gp + go);
        u32 w0 = (u32)gv[0], w1 = (u32)(gv[0] >> 32);
        u32 w2 = (u32)gv[1], w3 = (u32)(gv[1] >> 32);
        g[hh][0] = lo16(w0); g[hh][1] = hi16(w0);
        g[hh][2] = lo16(w1); g[hh][3] = hi16(w1);
        g[hh][4] = lo16(w2); g[hh][5] = hi16(w2);
        g[hh][6] = lo16(w3); g[hh][7] = hi16(w3);
        if (!act)
            #pragma unroll
            for (int i = 0; i < 8; ++i) g[hh][i] = 0.f;
    }
    v2u hp[6];
    #pragma unroll
    for (int d = 0; d < 6; ++d)
        hp[d] = *(const v2u*)(h + (long)eid[d] * PD + cl * 8);

    float s0[6], s1[6], s2[6], s3[6];
    #pragma unroll
    for (int d = 0; d < 6; ++d) {
        u32 w0 = (u32)hp[d][0], w1 = (u32)(hp[d][0] >> 32);
        u32 w2 = (u32)hp[d][1], w3 = (u32)(hp[d][1] >> 32);
        float hf[8] = {lo16(w0), hi16(w0), lo16(w1), hi16(w1),
                       lo16(w2), hi16(w2), lo16(w3), hi16(w3)};
        float p0 = 0, p1 = 0, p2 = 0, p3 = 0;
        #pragma unroll
        for (int i = 0; i < 8; ++i) {
            p0 += g[0][i] * hf[i];
            p1 += g[1][i] * hf[i];
            p2 += g[2][i] * hf[i];
            p3 += g[3][i] * hf[i];
        }
        #pragma unroll
        for (int off = 32; off; off >>= 1) {
            p0 += __shfl_xor(p0, off);
            p1 += __shfl_xor(p1, off);
            p2 += __shfl_xor(p2, off);
            p3 += __shfl_xor(p3, off);
        }
        s0[d] = p0; s1[d] = p1; s2[d] = p2; s3[d] = p3;
    }

    const float scale = 0.1154700538379252f; // 1/sqrt(75)
    float at[4][6];
    {
        float m0 = -1e30f, m1 = -1e30f, m2 = -1e30f, m3 = -1e30f;
        #pragma unroll
        for (int d = 0; d < 6; ++d) {
            s0[d] *= scale; s1[d] *= scale; s2[d] *= scale; s3[d] *= scale;
            m0 = fmaxf(m0, s0[d]); m1 = fmaxf(m1, s1[d]);
            m2 = fmaxf(m2, s2[d]); m3 = fmaxf(m3, s3[d]);
        }
        float t0 = 0, t1 = 0, t2 = 0, t3 = 0;
        #pragma unroll
        for (int d = 0; d < 6; ++d) {
            at[0][d] = expf(s0[d] - m0); t0 += at[0][d];
            at[1][d] = expf(s1[d] - m1); t1 += at[1][d];
            at[2][d] = expf(s2[d] - m2); t2 += at[2][d];
            at[3][d] = expf(s3[d] - m3); t3 += at[3][d];
        }
        t0 = 1.f / t0; t1 = 1.f / t1; t2 = 1.f / t2; t3 = 1.f / t3;
        #pragma unroll
        for (int d = 0; d < 6; ++d) {
            at[0][d] *= t0; at[1][d] *= t1; at[2][d] *= t2; at[3][d] *= t3;
        }
    }

    float u[4][8];
    #pragma unroll
    for (int hh = 0; hh < 4; ++hh)
        #pragma unroll
        for (int i = 0; i < 8; ++i) u[hh][i] = 0.f;
    #pragma unroll
    for (int d = 0; d < 6; ++d) {
        u32 w0 = (u32)hp[d][0], w1 = (u32)(hp[d][0] >> 32);
        u32 w2 = (u32)hp[d][1], w3 = (u32)(hp[d][1] >> 32);
        float hf[8] = {lo16(w0), hi16(w0), lo16(w1), hi16(w1),
                       lo16(w2), hi16(w2), lo16(w3), hi16(w3)};
        #pragma unroll
        for (int i = 0; i < 8; ++i) {
            u[0][i] += at[0][d] * hf[i];
            u[1][i] += at[1][d] * hf[i];
            u[2][i] += at[2][d] * hf[i];
            u[3][i] += at[3][d] * hf[i];
        }
    }
    if (act) {
        #pragma unroll
        for (int hh = 0; hh < 4; ++hh) {
            bf16* Up = (hh == 0) ? U0 : (hh == 1) ? U1 : (hh == 2) ? U2 : U3;
            v2u r;
            r[0] = (ull)cvtpk(u[hh][0], u[hh][1]) |
                   ((ull)cvtpk(u[hh][2], u[hh][3]) << 32);
            r[1] = (ull)cvtpk(u[hh][4], u[hh][5]) |
                   ((ull)cvtpk(u[hh][6], u[hh][7]) << 32);
            *(v2u*)(Up + go) = r;
        }
    }
}

// ---- f32[rows,300] -> bf16[rows,320] padded ----
__global__ __launch_bounds__(256)
void conv_k(const float* __restrict__ in, bf16* __restrict__ out, int rows)
{
    long idx = (long)blockIdx.x * 256 + threadIdx.x;
    if (idx >= (long)rows * 40) return;
    int r = (int)(idx / 40), ch = (int)(idx - (long)r * 40);
    int c4 = ch * 2;
    float4 a = {0, 0, 0, 0}, b = {0, 0, 0, 0};
    if (c4 < 75)     a = *(const float4*)(in + (long)r * DD + c4 * 4);
    if (c4 + 1 < 75) b = *(const float4*)(in + (long)r * DD + c4 * 4 + 4);
    v2u v;
    v[0] = (ull)cvtpk(a.x, a.y) | ((ull)cvtpk(a.z, a.w) << 32);
    v[1] = (ull)cvtpk(b.x, b.y) | ((ull)cvtpk(b.z, b.w) << 32);
    *(v2u*)(out + (long)r * PD + ch * 8) = v;
}

// ---- weight transpose+convert: BT[c][k] = W[k][c], 320x320 bf16 pad ----
__global__ __launch_bounds__(256)
void tw_k(const float* __restrict__ W, bf16* __restrict__ BT)
{
    int idx = blockIdx.x * 256 + threadIdx.x;
    if (idx >= 320 * 320) return;
    int nn = idx / 320, kk = idx - nn * 320;
    u16 v = 0;
    if (nn < DD && kk < DD) v = f2bf(W[kk * DD + nn]);
    ((u16*)BT)[idx] = v;
}

// ---- f32 transpose: WT[c][r] = W[r][c], [300,300] -> [320,320] pad ----
__global__ __launch_bounds__(256)
void twf_k(const float* __restrict__ W, float* __restrict__ WT)
{
    __shared__ float t[32][33];
    int bx = blockIdx.x % 10, by = blockIdx.x / 10;
    int r0 = by * 32, c0 = bx * 32;
    int tx = threadIdx.x & 31, ty = threadIdx.x >> 5;
    #pragma unroll
    for (int i = 0; i < 4; ++i) {
        int r = r0 + ty + i * 8, c = c0 + tx;
        t[ty + i * 8][tx] = (r < DD && c < DD) ? W[r * DD + c] : 0.f;
    }
    __syncthreads();
    #pragma unroll
    for (int i = 0; i < 4; ++i)
        WT[(c0 + ty + i * 8) * 320 + r0 + tx] = t[tx][ty + i * 8];
}

// ---- composed QK (coalesced): slab[c][k] = sum_j WqT[jb+j][k]*Wk[ci][jb+j] ----
__global__ __launch_bounds__(256)
void wqk_k(const float* __restrict__ WqT, const float* __restrict__ Wk,
           bf16* __restrict__ slab)
{
    int idx = blockIdx.x * 256 + threadIdx.x;
    if (idx >= 1280 * 320) return;
    int c = idx / 320, k = idx - c * 320;
    int hh = c / 320;
    int ci = c - hh * 320;
    float v = 0.f;
    if (ci < DD && k < DD) {
        int jb = hh * 75;
        for (int j = 0; j < 75; ++j)
            v += WqT[(jb + j) * 320 + k] * Wk[ci * DD + jb + j];
    }
    ((u16*)slab)[idx] = f2bf(v);
}

// ---- composed V-O (coalesced): 5 slots: s<4: Wv_h@Wo_h ; s=4: Wv@Wo ----
__global__ __launch_bounds__(256)
void wcomp_k(const float* __restrict__ WvT, const float* __restrict__ Wo,
             bf16* __restrict__ slab)
{
    int idx = blockIdx.x * 256 + threadIdx.x;
    if (idx >= 5 * 320 * 320) return;
    int s = idx / 102400, rem = idx - s * 102400;
    int c = rem / 320, k = rem - c * 320;
    float v = 0.f;
    if (c < DD && k < DD) {
        int jb = (s < 4) ? s * 75 : 0;
        int jn = (s < 4) ? 75 : 300;
        for (int j = 0; j < jn; ++j)
            v += WvT[(jb + j) * 320 + k] * Wo[(jb + j) * DD + c];
    }
    ((u16*)slab)[idx] = f2bf(v);
}

// ---- padded bias vectors (8 x 320 f32) ----
__global__ void bias_k(const float* __restrict__ WkT, const float* __restrict__ Wo,
                       const float* __restrict__ bq, const float* __restrict__ bv,
                       const float* __restrict__ bo, const float* __restrict__ bmp,
                       const float* __restrict__ blast, float* __restrict__ outb)
{
    int a = blockIdx.x, i = threadIdx.x; // 8 x 320
    float v = 0.f;
    if (i < DD) {
        if (a < 4) {
            for (int j = 0; j < 75; ++j)
                v += bq[a * 75 + j] * WkT[(a * 75 + j) * 320 + i];
        } else if (a == 4) {
            for (int j = 0; j < DD; ++j) v += bv[j] * Wo[j * DD + i];
            v += bo[i];
        } else if (a == 5) v = bmp[i];
        else if (a == 6) v = bmp[DD + i];
        else v = blast[i];
    }
    outb[a * 320 + i] = v;
}

extern "C" void kernel_launch(void* const* d_in, const int* in_sizes, int n_in,
                              void* d_out, int out_size, void* d_ws, size_t ws_size,
                              hipStream_t stream)
{
    const float* f     = (const float*)d_in[0];
    const float* x     = (const float*)d_in[1];
    const float* Wq    = (const float*)d_in[2];
    const float* bq    = (const float*)d_in[3];
    const float* Wk    = (const float*)d_in[4];
    const float* bv    = (const float*)d_in[7];
    const float* Wv    = (const float*)d_in[6];
    const float* Wo    = (const float*)d_in[8];
    const float* bo    = (const float*)d_in[9];
    const float* Wmp   = (const float*)d_in[10];
    const float* bmp   = (const float*)d_in[11];
    const float* Wlast = (const float*)d_in[12];
    const float* blast = (const float*)d_in[13];
    const int*   src   = (const int*)d_in[14];
    const int*   nbr   = (const int*)d_in[16];

    float* out     = (float*)d_out;
    float* f_final = out;
    float* h_final = out + (long)NN * DD;

    // ws layout (ends ~772.7 MB; proven-safe bound ~901.8 MB):
    char* ws = (char*)d_ws;
    bf16* xb  = (bf16*)(ws);                   // [E,320] 192e6
    bf16* h1b = (bf16*)(ws + 192000000LL);     // [E,320]
    bf16* fb  = (bf16*)(ws + 576000000LL);     // [N,320] 32e6
    bf16* G0  = (bf16*)(ws + 608000000LL);     // [N,320] x4 (alias U)
    bf16* G1  = (bf16*)(ws + 640000000LL);
    bf16* G2  = (bf16*)(ws + 672000000LL);
    bf16* G3  = (bf16*)(ws + 704000000LL);
    bf16* FHb = (bf16*)(ws + 736000000LL);     // [N,320]
    bf16* WT  = (bf16*)(ws + 768000000LL);     // 14 slots x 204800 B
    float* BIAS = (float*)(ws + 771300000LL);  // 8 x 320 f32
    float* WqT  = (float*)(ws + 771400000LL);  // 320x320 f32 each
    float* WkT  = (float*)(ws + 771850000LL);
    float* WvT  = (float*)(ws + 772300000LL);
    auto slot = [&](int i) { return WT + (long)i * 320 * 320; };
    // slots: 0-3 qk heads | 4-8 fh(comp0..3,vo) | 9 mp0 | 10 mp1 | 11-13 last
    bf16* qk   = slot(0);
    bf16* fh5  = slot(4);
    float* g0p = BIAS;
    float* b2p = BIAS + 1280;
    float* bm0p = BIAS + 1600;  float* bm1p = BIAS + 1920;
    float* blp = BIAS + 2240;

    dim3 blk(256), blk5(512);
    const int gN = (NN + 63) / 64;   // 782
    const int gE = (EE + 63) / 64;   // 4688

    conv_k<<<(int)(((long)EE * 40 + 255) / 256), blk, 0, stream>>>(x, xb, EE);
    conv_k<<<(int)(((long)NN * 40 + 255) / 256), blk, 0, stream>>>(f, fb, NN);
    twf_k<<<100, blk, 0, stream>>>(Wq, WqT);
    twf_k<<<100, blk, 0, stream>>>(Wk, WkT);
    twf_k<<<100, blk, 0, stream>>>(Wv, WvT);
    wqk_k<<<1600, blk, 0, stream>>>(WqT, Wk, qk);
    wcomp_k<<<2000, blk, 0, stream>>>(WvT, Wo, fh5);
    tw_k<<<400, blk, 0, stream>>>(Wmp, slot(9));
    tw_k<<<400, blk, 0, stream>>>(Wmp + 90000, slot(10));
    tw_k<<<400, blk, 0, stream>>>(Wlast, slot(11));
    tw_k<<<400, blk, 0, stream>>>(Wlast + 90000, slot(12));
    tw_k<<<400, blk, 0, stream>>>(Wlast + 180000, slot(13));
    bias_k<<<8, 320, 0, stream>>>(WkT, Wo, bq, bv, bo, bmp, blast, BIAS);

    for (int it = 0; it < 2; ++it) {
        const bf16* hb  = it ? h1b : xb;
        const bf16* fhb = it ? FHb : fb;
        const bf16* mpW = it ? slot(10) : slot(9);
        const float* bmP = it ? bm1p : bm0p;
        // G_h = f_h @ Wqk_h + g_h   (grid.y = 4 heads)
        gemm_mfma<E_BIAS, O_BF16, 1><<<dim3(gN, 4), blk5, 0, stream>>>(
            fhb, nullptr, nullptr, nullptr, nullptr, nullptr, nullptr, nullptr,
            qk, g0p, nullptr, nullptr, G0, NN, 16000000);
        // scores + softmax + U_h (U aliases G)
        scoreU_k<<<(NN + 3) / 4, blk, 0, stream>>>(G0, G1, G2, G3, hb, nbr,
                                                   G0, G1, G2, G3);
        // f_h_new = sum_h U_h@Wcomp_h + f_h@Wvo + b2
        gemm_mfma<E_BIAS, O_BF16, 5><<<gN, blk5, 0, stream>>>(
            G0, G1, G2, G3, fhb, nullptr, nullptr, nullptr, fh5, b2p, nullptr,
            nullptr, FHb, NN, 0);
        // h_new = relu(x + (f_h[src]-h[rev])@Wmp + bmp)  (register-staged gather)
        if (it == 0) {
            gemm_mfma<E_MPG, O_BF16, 1><<<gE, blk5, 0, stream>>>(
                FHb, hb, nullptr, nullptr, nullptr, src, nullptr, nullptr,
                mpW, bm0p, xb, nullptr, h1b, EE, 0);
        } else {
            gemm_mfma<E_MPG, O_F32, 1><<<gE, blk5, 0, stream>>>(
                FHb, hb, nullptr, nullptr, nullptr, src, nullptr, nullptr,
                mpW, bm1p, xb, h_final, nullptr, EE, 0);
        }
    }

    // f_final = [mail | f_h | f] @ W_last + b_last  (mail gather fused in seg0)
    gemm_mfma<E_LAST, O_F32, 3><<<gN, blk5, 0, stream>>>(
        nullptr, FHb, fb, nullptr, nullptr, nullptr, h_final, nbr,
        slot(11), blp, nullptr, f_final, nullptr, NN, 0);
}

// Round 14
// 2170.162 us; speedup vs baseline: 1.7489x; 1.0217x over previous
//
#include <hip/hip_runtime.h>
#include <hip/hip_bf16.h>

typedef unsigned long long ull;
typedef unsigned int u32;
typedef unsigned short u16;
typedef __hip_bfloat16 bf16;
typedef __attribute__((ext_vector_type(8))) short v8s;
typedef __attribute__((ext_vector_type(4))) float v4f;
typedef __attribute__((ext_vector_type(2))) ull v2u;

#define NN 50000
#define DD 300
#define PD 320
#define EE (NN*6)

__device__ __forceinline__ u16 f2bf(float f) {
    u32 u = __float_as_uint(f);
    u32 r = u + 0x7FFFu + ((u >> 16) & 1u);
    return (u16)(r >> 16);
}
__device__ __forceinline__ u32 cvtpk(float lo, float hi) {
    u32 r;
    asm("v_cvt_pk_bf16_f32 %0, %1, %2" : "=v"(r) : "v"(lo), "v"(hi));
    return r;
}
__device__ __forceinline__ float lo16(u32 u) { return __uint_as_float(u << 16); }
__device__ __forceinline__ float hi16(u32 u) { return __uint_as_float(u & 0xffff0000u); }

__device__ __forceinline__ u32 sub2bf(u32 a, u32 b) {
    return cvtpk(lo16(a) - lo16(b), hi16(a) - hi16(b));
}
__device__ __forceinline__ ull sub4bf(ull a, ull b) {
    u32 l = sub2bf((u32)a, (u32)b);
    u32 h = sub2bf((u32)(a >> 32), (u32)(b >> 32));
    return (ull)l | ((ull)h << 32);
}

// async global->LDS, 16 B/lane: lane's data lands at lds_base + lane*16.
__device__ __forceinline__ void gl16(const void* g, void* l) {
    __builtin_amdgcn_global_load_lds(
        (const __attribute__((address_space(1))) u32*)g,
        (__attribute__((address_space(3))) u32*)l, 16, 0, 0);
}

enum { E_BIAS = 0, E_MPG = 1 };
enum { O_F32 = 1, O_BF16 = 2 };

// C[M,320] = sum_seg A_seg[M,320] @ BT_seg (+bias) (+epi). BT bf16 [col][320].
// 8 waves (2 row-halves x 4 col-quarters), acc[2][5], 64 rows/block, 40KB LDS.
// E_BIAS: linear gl16 staging (involutory source chunk swizzle, linear dest).
// E_MPG : register-staged A0[src[row]] - A1[row^1]; ISSUE-EARLY: all 10 loads
//         in flight before any sub/ds_write (T14). Writer: relu(x + val),
//         x loads all issued before processing. grid.y slices BT/bias/Cb.
template<int EPI, int OUTM, int NSEG>
__global__ __launch_bounds__(512, 4)
void gemm_mfma(const bf16* __restrict__ A0, const bf16* __restrict__ A1,
               const bf16* __restrict__ A2, const bf16* __restrict__ A3,
               const bf16* __restrict__ A4,
               const int* __restrict__ srcidx,
               const bf16* __restrict__ BT, const float* __restrict__ bias0,
               const bf16* __restrict__ xepi,
               float* __restrict__ Cf, bf16* __restrict__ Cb0,
               int M, long ycb)
{
    __shared__ __align__(16) char Als[64 * 640];
    const int tid = threadIdx.x;
    const int wave = tid >> 6, lane = tid & 63;
    const int l15 = lane & 15, l4 = lane >> 4;
    const int wr = wave >> 2, wc = wave & 3;
    const int rowBase = blockIdx.x * 64;
    const int gy = blockIdx.y;
    BT += (long)gy * 102400;
    if (bias0) bias0 += (long)gy * 320;
    if (Cb0) Cb0 += (long)gy * ycb;

    v4f acc[2][5];
    const v4f vzero = {0.f, 0.f, 0.f, 0.f};
    #pragma unroll
    for (int mt = 0; mt < 2; ++mt)
        #pragma unroll
        for (int nt = 0; nt < 5; ++nt) acc[mt][nt] = vzero;

    for (int seg = 0; seg < NSEG; ++seg) {
        const bf16* As = (seg == 0) ? A0 : (seg == 1 ? A1 : (seg == 2 ? A2 :
                         (seg == 3 ? A3 : A4)));
        if (seg) __syncthreads();
        if (EPI == E_MPG) {
            // issue phase: all 10 v2u loads outstanding before any use
            v2u av[5], bv[5];
            #pragma unroll
            for (int s = 0; s < 5; ++s) {
                int c = tid + 512 * s;
                int r = c / 40, ch = c - r * 40;
                int grow = rowBase + r;
                grow = (grow < M) ? grow : (M - 1);
                int sr = srcidx[grow];
                av[s] = *(const v2u*)(A0 + (long)sr * PD + ch * 8);
                bv[s] = *(const v2u*)(A1 + (long)(grow ^ 1) * PD + ch * 8);
            }
            // consume phase
            #pragma unroll
            for (int s = 0; s < 5; ++s) {
                int c = tid + 512 * s;
                int r = c / 40;
                v2u v;
                v[0] = sub4bf(av[s][0], bv[s][0]);
                v[1] = sub4bf(av[s][1], bv[s][1]);
                *(v2u*)(Als + ((c * 16) ^ ((r & 7) << 4))) = v;
            }
        } else {
            #pragma unroll
            for (int s = 0; s < 5; ++s) {
                int c = tid + 512 * s;
                int r = c / 40, ch = c - r * 40;
                int grow = rowBase + r;
                grow = (grow < M) ? grow : (M - 1);
                int chs = ch ^ (r & 7);               // involutory chunk swizzle
                gl16(As + (long)grow * PD + chs * 8,
                     Als + (wave * 64 + 512 * s) * 16);  // wave-uniform base
            }
        }
        __syncthreads();

        const bf16* BTs = BT + (long)seg * 102400;
        #pragma unroll
        for (int ks = 0; ks < 10; ++ks) {
            v8s af[2];
            #pragma unroll
            for (int mt = 0; mt < 2; ++mt) {
                int rowL = wr * 32 + mt * 16 + l15;
                af[mt] = *(const v8s*)(Als +
                    ((rowL * 640 + ks * 64 + l4 * 16) ^ ((rowL & 7) << 4)));
            }
            #pragma unroll
            for (int nt = 0; nt < 5; ++nt) {
                int col = wc * 80 + nt * 16 + l15;
                v8s bfr = *(const v8s*)(BTs + (long)col * PD + ks * 32 + l4 * 8);
                #pragma unroll
                for (int mt = 0; mt < 2; ++mt)
                    acc[mt][nt] = __builtin_amdgcn_mfma_f32_16x16x32_bf16(
                        af[mt], bfr, acc[mt][nt], 0, 0, 0);
            }
        }
    }

    // ---- phase A: acc (+bias) -> LDS bf16 tile, swizzled ----
    __syncthreads();
    #pragma unroll
    for (int nt = 0; nt < 5; ++nt) {
        int col = wc * 80 + nt * 16 + l15;
        float bvv = bias0 ? bias0[col] : 0.f;
        #pragma unroll
        for (int mt = 0; mt < 2; ++mt) {
            #pragma unroll
            for (int rr = 0; rr < 4; ++rr) {
                int rowL = wr * 32 + mt * 16 + l4 * 4 + rr;
                *(u16*)(Als + ((rowL * 640 + col * 2) ^ (((rowL >> 2) & 7) << 4)))
                    = f2bf(acc[mt][nt][rr] + bvv);
            }
        }
    }
    __syncthreads();

    // ---- phase B: writer (x loads issued before processing) ----
    v2u xvv[5];
    if (EPI == E_MPG) {
        #pragma unroll
        for (int s = 0; s < 5; ++s) {
            int c = tid + 512 * s;
            int r = c / 40, ch = c - r * 40;
            int grow = rowBase + r;
            grow = (grow < M) ? grow : (M - 1);
            xvv[s] = *(const v2u*)(xepi + (long)grow * PD + ch * 8);
        }
    }
    #pragma unroll
    for (int s = 0; s < 5; ++s) {
        int c = tid + 512 * s;
        int r = c / 40, ch = c - r * 40;
        int grow = rowBase + r;
        if (grow >= M) continue;
        v2u val = *(const v2u*)(Als + ((c * 16) ^ (((r >> 2) & 7) << 4)));
        if (EPI == E_MPG) {
            v2u xv = xvv[s];
            #pragma unroll
            for (int w = 0; w < 2; ++w) {
                u32 a0 = (u32)val[w], a1 = (u32)(val[w] >> 32);
                u32 x0 = (u32)xv[w],  x1 = (u32)(xv[w] >> 32);
                u32 r0 = cvtpk(fmaxf(lo16(a0) + lo16(x0), 0.f),
                               fmaxf(hi16(a0) + hi16(x0), 0.f));
                u32 r1 = cvtpk(fmaxf(lo16(a1) + lo16(x1), 0.f),
                               fmaxf(hi16(a1) + hi16(x1), 0.f));
                val[w] = (ull)r0 | ((ull)r1 << 32);
            }
        }
        if (OUTM & O_BF16)
            *(v2u*)(Cb0 + (long)grow * PD + ch * 8) = val;
        if (OUTM & O_F32) {
            int col0 = ch * 8;
            if (col0 < DD) {
                u32 a0 = (u32)val[0], a1 = (u32)(val[0] >> 32);
                float4 lo = {lo16(a0), hi16(a0), lo16(a1), hi16(a1)};
                *(float4*)(Cf + (long)grow * DD + col0) = lo;
                if (col0 + 4 < DD) {
                    u32 b0 = (u32)val[1], b1 = (u32)(val[1] >> 32);
                    float4 hi4 = {lo16(b0), hi16(b0), lo16(b1), hi16(b1)};
                    *(float4*)(Cf + (long)grow * DD + col0 + 4) = hi4;
                }
            }
        }
    }
}

// ---- scoreU: s[h,d] = scale*(h_d . G_h[n]); softmax; U_h = sum_d a*h_d ----
__global__ __launch_bounds__(256)
void scoreU_k(const bf16* __restrict__ G0, const bf16* __restrict__ G1,
              const bf16* __restrict__ G2, const bf16* __restrict__ G3,
              const bf16* __restrict__ h, const int* __restrict__ nbr,
              bf16* __restrict__ U0, bf16* __restrict__ U1,
              bf16* __restrict__ U2, bf16* __restrict__ U3)
{
    int wave = threadIdx.x >> 6, lane = threadIdx.x & 63;
    int n = blockIdx.x * 4 + wave;
    if (n >= NN) return;
    int eid[6];
    #pragma unroll
    for (int d = 0; d < 6; ++d) eid[d] = nbr[n * 6 + d];

    bool act = lane < 40;
    int cl = act ? lane : 0;
    long go = (long)n * PD + cl * 8;

    float g[4][8];
    #pragma unroll
    for (int hh = 0; hh < 4; ++hh) {
        const bf16* Gp = (hh == 0) ? G0 : (hh == 1) ? G1 : (hh == 2) ? G2 : G3;
        v2u gv = *(const v2u*)(Gp + go);
        u32 w0 = (u32)gv[0], w1 = (u32)(gv[0] >> 32);
        u32 w2 = (u32)gv[1], w3 = (u32)(gv[1] >> 32);
        g[hh][0] = lo16(w0); g[hh][1] = hi16(w0);
        g[hh][2] = lo16(w1); g[hh][3] = hi16(w1);
        g[hh][4] = lo16(w2); g[hh][5] = hi16(w2);
        g[hh][6] = lo16(w3); g[hh][7] = hi16(w3);
        if (!act)
            #pragma unroll
            for (int i = 0; i < 8; ++i) g[hh][i] = 0.f;
    }
    v2u hp[6];
    #pragma unroll
    for (int d = 0; d < 6; ++d)
        hp[d] = *(const v2u*)(h + (long)eid[d] * PD + cl * 8);

    float s0[6], s1[6], s2[6], s3[6];
    #pragma unroll
    for (int d = 0; d < 6; ++d) {
        u32 w0 = (u32)hp[d][0], w1 = (u32)(hp[d][0] >> 32);
        u32 w2 = (u32)hp[d][1], w3 = (u32)(hp[d][1] >> 32);
        float hf[8] = {lo16(w0), hi16(w0), lo16(w1), hi16(w1),
                       lo16(w2), hi16(w2), lo16(w3), hi16(w3)};
        float p0 = 0, p1 = 0, p2 = 0, p3 = 0;
        #pragma unroll
        for (int i = 0; i < 8; ++i) {
            p0 += g[0][i] * hf[i];
            p1 += g[1][i] * hf[i];
            p2 += g[2][i] * hf[i];
            p3 += g[3][i] * hf[i];
        }
        #pragma unroll
        for (int off = 32; off; off >>= 1) {
            p0 += __shfl_xor(p0, off);
            p1 += __shfl_xor(p1, off);
            p2 += __shfl_xor(p2, off);
            p3 += __shfl_xor(p3, off);
        }
        s0[d] = p0; s1[d] = p1; s2[d] = p2; s3[d] = p3;
    }

    const float scale = 0.1154700538379252f; // 1/sqrt(75)
    float at[4][6];
    {
        float m0 = -1e30f, m1 = -1e30f, m2 = -1e30f, m3 = -1e30f;
        #pragma unroll
        for (int d = 0; d < 6; ++d) {
            s0[d] *= scale; s1[d] *= scale; s2[d] *= scale; s3[d] *= scale;
            m0 = fmaxf(m0, s0[d]); m1 = fmaxf(m1, s1[d]);
            m2 = fmaxf(m2, s2[d]); m3 = fmaxf(m3, s3[d]);
        }
        float t0 = 0, t1 = 0, t2 = 0, t3 = 0;
        #pragma unroll
        for (int d = 0; d < 6; ++d) {
            at[0][d] = expf(s0[d] - m0); t0 += at[0][d];
            at[1][d] = expf(s1[d] - m1); t1 += at[1][d];
            at[2][d] = expf(s2[d] - m2); t2 += at[2][d];
            at[3][d] = expf(s3[d] - m3); t3 += at[3][d];
        }
        t0 = 1.f / t0; t1 = 1.f / t1; t2 = 1.f / t2; t3 = 1.f / t3;
        #pragma unroll
        for (int d = 0; d < 6; ++d) {
            at[0][d] *= t0; at[1][d] *= t1; at[2][d] *= t2; at[3][d] *= t3;
        }
    }

    float u[4][8];
    #pragma unroll
    for (int hh = 0; hh < 4; ++hh)
        #pragma unroll
        for (int i = 0; i < 8; ++i) u[hh][i] = 0.f;
    #pragma unroll
    for (int d = 0; d < 6; ++d) {
        u32 w0 = (u32)hp[d][0], w1 = (u32)(hp[d][0] >> 32);
        u32 w2 = (u32)hp[d][1], w3 = (u32)(hp[d][1] >> 32);
        float hf[8] = {lo16(w0), hi16(w0), lo16(w1), hi16(w1),
                       lo16(w2), hi16(w2), lo16(w3), hi16(w3)};
        #pragma unroll
        for (int i = 0; i < 8; ++i) {
            u[0][i] += at[0][d] * hf[i];
            u[1][i] += at[1][d] * hf[i];
            u[2][i] += at[2][d] * hf[i];
            u[3][i] += at[3][d] * hf[i];
        }
    }
    if (act) {
        #pragma unroll
        for (int hh = 0; hh < 4; ++hh) {
            bf16* Up = (hh == 0) ? U0 : (hh == 1) ? U1 : (hh == 2) ? U2 : U3;
            v2u r;
            r[0] = (ull)cvtpk(u[hh][0], u[hh][1]) |
                   ((ull)cvtpk(u[hh][2], u[hh][3]) << 32);
            r[1] = (ull)cvtpk(u[hh][4], u[hh][5]) |
                   ((ull)cvtpk(u[hh][6], u[hh][7]) << 32);
            *(v2u*)(Up + go) = r;
        }
    }
}

// ---- mail from f32 h_final: mail[n] = sum_d h[nbr[n,d]] -> bf16 padded ----
__global__ __launch_bounds__(256)
void mailf_k(const float* __restrict__ h, const int* __restrict__ nbr,
             bf16* __restrict__ mail)
{
    int idx = blockIdx.x * 256 + threadIdx.x;
    if (idx >= NN * 80) return;
    int n = idx / 80, c4 = idx - n * 80;
    float4 s = {0.f, 0.f, 0.f, 0.f};
    if (c4 < 75) {
        const int* e = nbr + n * 6;
        #pragma unroll
        for (int d = 0; d < 6; ++d) {
            float4 v = *(const float4*)(h + (long)e[d] * DD + c4 * 4);
            s.x += v.x; s.y += v.y; s.z += v.z; s.w += v.w;
        }
    }
    ull r = (ull)cvtpk(s.x, s.y) | ((ull)cvtpk(s.z, s.w) << 32);
    *(ull*)(mail + (long)n * PD + c4 * 4) = r;
}

// ---- f32[rows,300] -> bf16[rows,320] padded ----
__global__ __launch_bounds__(256)
void conv_k(const float* __restrict__ in, bf16* __restrict__ out, int rows)
{
    long idx = (long)blockIdx.x * 256 + threadIdx.x;
    if (idx >= (long)rows * 40) return;
    int r = (int)(idx / 40), ch = (int)(idx - (long)r * 40);
    int c4 = ch * 2;
    float4 a = {0, 0, 0, 0}, b = {0, 0, 0, 0};
    if (c4 < 75)     a = *(const float4*)(in + (long)r * DD + c4 * 4);
    if (c4 + 1 < 75) b = *(const float4*)(in + (long)r * DD + c4 * 4 + 4);
    v2u v;
    v[0] = (ull)cvtpk(a.x, a.y) | ((ull)cvtpk(a.z, a.w) << 32);
    v[1] = (ull)cvtpk(b.x, b.y) | ((ull)cvtpk(b.z, b.w) << 32);
    *(v2u*)(out + (long)r * PD + ch * 8) = v;
}

// ---- weight transpose+convert: BT[c][k] = W[k][c], 320x320 bf16 pad ----
__global__ __launch_bounds__(256)
void tw_k(const float* __restrict__ W, bf16* __restrict__ BT)
{
    int idx = blockIdx.x * 256 + threadIdx.x;
    if (idx >= 320 * 320) return;
    int nn = idx / 320, kk = idx - nn * 320;
    u16 v = 0;
    if (nn < DD && kk < DD) v = f2bf(W[kk * DD + nn]);
    ((u16*)BT)[idx] = v;
}

// ---- f32 transpose: WT[c][r] = W[r][c], [300,300] -> [320,320] pad ----
__global__ __launch_bounds__(256)
void twf_k(const float* __restrict__ W, float* __restrict__ WT)
{
    __shared__ float t[32][33];
    int bx = blockIdx.x % 10, by = blockIdx.x / 10;
    int r0 = by * 32, c0 = bx * 32;
    int tx = threadIdx.x & 31, ty = threadIdx.x >> 5;
    #pragma unroll
    for (int i = 0; i < 4; ++i) {
        int r = r0 + ty + i * 8, c = c0 + tx;
        t[ty + i * 8][tx] = (r < DD && c < DD) ? W[r * DD + c] : 0.f;
    }
    __syncthreads();
    #pragma unroll
    for (int i = 0; i < 4; ++i)
        WT[(c0 + ty + i * 8) * 320 + r0 + tx] = t[tx][ty + i * 8];
}

// ---- composed QK (coalesced): slab[c][k] = sum_j WqT[jb+j][k]*Wk[ci][jb+j] ----
__global__ __launch_bounds__(256)
void wqk_k(const float* __restrict__ WqT, const float* __restrict__ Wk,
           bf16* __restrict__ slab)
{
    int idx = blockIdx.x * 256 + threadIdx.x;
    if (idx >= 1280 * 320) return;
    int c = idx / 320, k = idx - c * 320;
    int hh = c / 320;
    int ci = c - hh * 320;
    float v = 0.f;
    if (ci < DD && k < DD) {
        int jb = hh * 75;
        for (int j = 0; j < 75; ++j)
            v += WqT[(jb + j) * 320 + k] * Wk[ci * DD + jb + j];
    }
    ((u16*)slab)[idx] = f2bf(v);
}

// ---- composed V-O (coalesced): 5 slots: s<4: Wv_h@Wo_h ; s=4: Wv@Wo ----
__global__ __launch_bounds__(256)
void wcomp_k(const float* __restrict__ WvT, const float* __restrict__ Wo,
             bf16* __restrict__ slab)
{
    int idx = blockIdx.x * 256 + threadIdx.x;
    if (idx >= 5 * 320 * 320) return;
    int s = idx / 102400, rem = idx - s * 102400;
    int c = rem / 320, k = rem - c * 320;
    float v = 0.f;
    if (c < DD && k < DD) {
        int jb = (s < 4) ? s * 75 : 0;
        int jn = (s < 4) ? 75 : 300;
        for (int j = 0; j < jn; ++j)
            v += WvT[(jb + j) * 320 + k] * Wo[(jb + j) * DD + c];
    }
    ((u16*)slab)[idx] = f2bf(v);
}

// ---- padded bias vectors (8 x 320 f32) ----
__global__ void bias_k(const float* __restrict__ WkT, const float* __restrict__ Wo,
                       const float* __restrict__ bq, const float* __restrict__ bv,
                       const float* __restrict__ bo, const float* __restrict__ bmp,
                       const float* __restrict__ blast, float* __restrict__ outb)
{
    int a = blockIdx.x, i = threadIdx.x; // 8 x 320
    float v = 0.f;
    if (i < DD) {
        if (a < 4) {
            for (int j = 0; j < 75; ++j)
                v += bq[a * 75 + j] * WkT[(a * 75 + j) * 320 + i];
        } else if (a == 4) {
            for (int j = 0; j < DD; ++j) v += bv[j] * Wo[j * DD + i];
            v += bo[i];
        } else if (a == 5) v = bmp[i];
        else if (a == 6) v = bmp[DD + i];
        else v = blast[i];
    }
    outb[a * 320 + i] = v;
}

extern "C" void kernel_launch(void* const* d_in, const int* in_sizes, int n_in,
                              void* d_out, int out_size, void* d_ws, size_t ws_size,
                              hipStream_t stream)
{
    const float* f     = (const float*)d_in[0];
    const float* x     = (const float*)d_in[1];
    const float* Wq    = (const float*)d_in[2];
    const float* bq    = (const float*)d_in[3];
    const float* Wk    = (const float*)d_in[4];
    const float* bv    = (const float*)d_in[7];
    const float* Wv    = (const float*)d_in[6];
    const float* Wo    = (const float*)d_in[8];
    const float* bo    = (const float*)d_in[9];
    const float* Wmp   = (const float*)d_in[10];
    const float* bmp   = (const float*)d_in[11];
    const float* Wlast = (const float*)d_in[12];
    const float* blast = (const float*)d_in[13];
    const int*   src   = (const int*)d_in[14];
    const int*   nbr   = (const int*)d_in[16];

    float* out     = (float*)d_out;
    float* f_final = out;
    float* h_final = out + (long)NN * DD;

    // ws layout (ends ~772.7 MB; proven-safe bound ~901.8 MB):
    char* ws = (char*)d_ws;
    bf16* xb  = (bf16*)(ws);                   // [E,320] 192e6
    bf16* h1b = (bf16*)(ws + 192000000LL);     // [E,320]
    bf16* fb  = (bf16*)(ws + 576000000LL);     // [N,320] 32e6
    bf16* G0  = (bf16*)(ws + 608000000LL);     // [N,320] x4 (alias U, mail)
    bf16* G1  = (bf16*)(ws + 640000000LL);
    bf16* G2  = (bf16*)(ws + 672000000LL);
    bf16* G3  = (bf16*)(ws + 704000000LL);
    bf16* FHb = (bf16*)(ws + 736000000LL);     // [N,320]
    bf16* WT  = (bf16*)(ws + 768000000LL);     // 14 slots x 204800 B
    float* BIAS = (float*)(ws + 771300000LL);  // 8 x 320 f32
    float* WqT  = (float*)(ws + 771400000LL);  // 320x320 f32 each
    float* WkT  = (float*)(ws + 771850000LL);
    float* WvT  = (float*)(ws + 772300000LL);
    auto slot = [&](int i) { return WT + (long)i * 320 * 320; };
    // slots: 0-3 qk heads | 4-8 fh(comp0..3,vo) | 9 mp0 | 10 mp1 | 11-13 last
    bf16* qk   = slot(0);
    bf16* fh5  = slot(4);
    float* g0p = BIAS;
    float* b2p = BIAS + 1280;
    float* bm0p = BIAS + 1600;  float* bm1p = BIAS + 1920;
    float* blp = BIAS + 2240;
    bf16* MLb = G0;

    dim3 blk(256), blk5(512);
    const int gN = (NN + 63) / 64;   // 782
    const int gE = (EE + 63) / 64;   // 4688

    conv_k<<<(int)(((long)EE * 40 + 255) / 256), blk, 0, stream>>>(x, xb, EE);
    conv_k<<<(int)(((long)NN * 40 + 255) / 256), blk, 0, stream>>>(f, fb, NN);
    twf_k<<<100, blk, 0, stream>>>(Wq, WqT);
    twf_k<<<100, blk, 0, stream>>>(Wk, WkT);
    twf_k<<<100, blk, 0, stream>>>(Wv, WvT);
    wqk_k<<<1600, blk, 0, stream>>>(WqT, Wk, qk);
    wcomp_k<<<2000, blk, 0, stream>>>(WvT, Wo, fh5);
    tw_k<<<400, blk, 0, stream>>>(Wmp, slot(9));
    tw_k<<<400, blk, 0, stream>>>(Wmp + 90000, slot(10));
    tw_k<<<400, blk, 0, stream>>>(Wlast, slot(11));
    tw_k<<<400, blk, 0, stream>>>(Wlast + 90000, slot(12));
    tw_k<<<400, blk, 0, stream>>>(Wlast + 180000, slot(13));
    bias_k<<<8, 320, 0, stream>>>(WkT, Wo, bq, bv, bo, bmp, blast, BIAS);

    for (int it = 0; it < 2; ++it) {
        const bf16* hb  = it ? h1b : xb;
        const bf16* fhb = it ? FHb : fb;
        const bf16* mpW = it ? slot(10) : slot(9);
        // G_h = f_h @ Wqk_h + g_h   (grid.y = 4 heads)
        gemm_mfma<E_BIAS, O_BF16, 1><<<dim3(gN, 4), blk5, 0, stream>>>(
            fhb, nullptr, nullptr, nullptr, nullptr, nullptr,
            qk, g0p, nullptr, nullptr, G0, NN, 16000000);
        // scores + softmax + U_h (U aliases G)
        scoreU_k<<<(NN + 3) / 4, blk, 0, stream>>>(G0, G1, G2, G3, hb, nbr,
                                                   G0, G1, G2, G3);
        // f_h_new = sum_h U_h@Wcomp_h + f_h@Wvo + b2
        gemm_mfma<E_BIAS, O_BF16, 5><<<gN, blk5, 0, stream>>>(
            G0, G1, G2, G3, fhb, nullptr, fh5, b2p, nullptr,
            nullptr, FHb, NN, 0);
        // h_new = relu(x + (f_h[src]-h[rev])@Wmp + bmp)  (register-staged gather)
        if (it == 0) {
            gemm_mfma<E_MPG, O_BF16, 1><<<gE, blk5, 0, stream>>>(
                FHb, hb, nullptr, nullptr, nullptr, src,
                mpW, bm0p, xb, nullptr, h1b, EE, 0);
        } else {
            gemm_mfma<E_MPG, O_F32, 1><<<gE, blk5, 0, stream>>>(
                FHb, hb, nullptr, nullptr, nullptr, src,
                mpW, bm1p, xb, h_final, nullptr, EE, 0);
        }
    }

    mailf_k<<<(NN * 80 + 255) / 256, blk, 0, stream>>>(h_final, nbr, MLb);
    gemm_mfma<E_BIAS, O_F32, 3><<<gN, blk5, 0, stream>>>(
        MLb, FHb, fb, nullptr, nullptr, nullptr, slot(11), blp,
        nullptr, f_final, nullptr, NN, 0);
}

// Round 15
// 2165.098 us; speedup vs baseline: 1.7530x; 1.0023x over previous
//
#include <hip/hip_runtime.h>
#include <hip/hip_bf16.h>

typedef unsigned long long ull;
typedef unsigned int u32;
typedef unsigned short u16;
typedef __hip_bfloat16 bf16;
typedef __attribute__((ext_vector_type(8))) short v8s;
typedef __attribute__((ext_vector_type(4))) float v4f;
typedef __attribute__((ext_vector_type(2))) ull v2u;

#define NN 50000
#define DD 300
#define PD 320
#define EE (NN*6)

__device__ __forceinline__ u16 f2bf(float f) {
    u32 u = __float_as_uint(f);
    u32 r = u + 0x7FFFu + ((u >> 16) & 1u);
    return (u16)(r >> 16);
}
__device__ __forceinline__ u32 cvtpk(float lo, float hi) {
    u32 r;
    asm("v_cvt_pk_bf16_f32 %0, %1, %2" : "=v"(r) : "v"(lo), "v"(hi));
    return r;
}
__device__ __forceinline__ float lo16(u32 u) { return __uint_as_float(u << 16); }
__device__ __forceinline__ float hi16(u32 u) { return __uint_as_float(u & 0xffff0000u); }

__device__ __forceinline__ u32 sub2bf(u32 a, u32 b) {
    return cvtpk(lo16(a) - lo16(b), hi16(a) - hi16(b));
}
__device__ __forceinline__ ull sub4bf(ull a, ull b) {
    u32 l = sub2bf((u32)a, (u32)b);
    u32 h = sub2bf((u32)(a >> 32), (u32)(b >> 32));
    return (ull)l | ((ull)h << 32);
}

// bijective XCD-aware block swizzle (m204): contiguous chunk per XCD.
__device__ __forceinline__ int xswz(int bid, int nwg) {
    int q = nwg >> 3, r = nwg & 7;
    int x = bid & 7, i = bid >> 3;
    return (x < r ? x * (q + 1) : r * (q + 1) + (x - r) * q) + i;
}

// async global->LDS, 16 B/lane: lane's data lands at lds_base + lane*16.
__device__ __forceinline__ void gl16(const void* g, void* l) {
    __builtin_amdgcn_global_load_lds(
        (const __attribute__((address_space(1))) u32*)g,
        (__attribute__((address_space(3))) u32*)l, 16, 0, 0);
}

enum { E_BIAS = 0, E_MPG = 1 };
enum { O_F32 = 1, O_BF16 = 2 };

// C[M,320] = sum_seg A_seg[M,320] @ BT_seg (+bias) (+epi). BT bf16 [col][320].
// 8 waves (2 row-halves x 4 col-quarters), acc[2][5], 64 rows/block, 40KB LDS.
// XCD-swizzled blockIdx.x for L2 locality (T1); setprio around MFMA (T5).
// E_BIAS: linear gl16 staging (involutory source chunk swizzle, linear dest).
// E_MPG : register-staged A0[src[row]] - A1[row^1], swizzled ds_write;
//         writer does relu(x + val). grid.y slices BT/bias/Cb.
template<int EPI, int OUTM, int NSEG>
__global__ __launch_bounds__(512, 4)
void gemm_mfma(const bf16* __restrict__ A0, const bf16* __restrict__ A1,
               const bf16* __restrict__ A2, const bf16* __restrict__ A3,
               const bf16* __restrict__ A4,
               const int* __restrict__ srcidx,
               const bf16* __restrict__ BT, const float* __restrict__ bias0,
               const bf16* __restrict__ xepi,
               float* __restrict__ Cf, bf16* __restrict__ Cb0,
               int M, long ycb)
{
    __shared__ __align__(16) char Als[64 * 640];
    const int tid = threadIdx.x;
    const int wave = tid >> 6, lane = tid & 63;
    const int l15 = lane & 15, l4 = lane >> 4;
    const int wr = wave >> 2, wc = wave & 3;
    const int rowBase = xswz(blockIdx.x, gridDim.x) * 64;
    const int gy = blockIdx.y;
    BT += (long)gy * 102400;
    if (bias0) bias0 += (long)gy * 320;
    if (Cb0) Cb0 += (long)gy * ycb;

    v4f acc[2][5];
    const v4f vzero = {0.f, 0.f, 0.f, 0.f};
    #pragma unroll
    for (int mt = 0; mt < 2; ++mt)
        #pragma unroll
        for (int nt = 0; nt < 5; ++nt) acc[mt][nt] = vzero;

    for (int seg = 0; seg < NSEG; ++seg) {
        const bf16* As = (seg == 0) ? A0 : (seg == 1 ? A1 : (seg == 2 ? A2 :
                         (seg == 3 ? A3 : A4)));
        if (seg) __syncthreads();
        if (EPI == E_MPG) {
            v2u av[5], bv[5];
            #pragma unroll
            for (int s = 0; s < 5; ++s) {
                int c = tid + 512 * s;
                int r = c / 40, ch = c - r * 40;
                int grow = rowBase + r;
                grow = (grow < M) ? grow : (M - 1);
                int sr = srcidx[grow];
                av[s] = *(const v2u*)(A0 + (long)sr * PD + ch * 8);
                bv[s] = *(const v2u*)(A1 + (long)(grow ^ 1) * PD + ch * 8);
            }
            #pragma unroll
            for (int s = 0; s < 5; ++s) {
                int c = tid + 512 * s;
                int r = c / 40;
                v2u v;
                v[0] = sub4bf(av[s][0], bv[s][0]);
                v[1] = sub4bf(av[s][1], bv[s][1]);
                *(v2u*)(Als + ((c * 16) ^ ((r & 7) << 4))) = v;
            }
        } else {
            #pragma unroll
            for (int s = 0; s < 5; ++s) {
                int c = tid + 512 * s;
                int r = c / 40, ch = c - r * 40;
                int grow = rowBase + r;
                grow = (grow < M) ? grow : (M - 1);
                int chs = ch ^ (r & 7);               // involutory chunk swizzle
                gl16(As + (long)grow * PD + chs * 8,
                     Als + (wave * 64 + 512 * s) * 16);  // wave-uniform base
            }
        }
        __syncthreads();

        const bf16* BTs = BT + (long)seg * 102400;
        __builtin_amdgcn_s_setprio(1);
        #pragma unroll
        for (int ks = 0; ks < 10; ++ks) {
            v8s af[2];
            #pragma unroll
            for (int mt = 0; mt < 2; ++mt) {
                int rowL = wr * 32 + mt * 16 + l15;
                af[mt] = *(const v8s*)(Als +
                    ((rowL * 640 + ks * 64 + l4 * 16) ^ ((rowL & 7) << 4)));
            }
            #pragma unroll
            for (int nt = 0; nt < 5; ++nt) {
                int col = wc * 80 + nt * 16 + l15;
                v8s bfr = *(const v8s*)(BTs + (long)col * PD + ks * 32 + l4 * 8);
                #pragma unroll
                for (int mt = 0; mt < 2; ++mt)
                    acc[mt][nt] = __builtin_amdgcn_mfma_f32_16x16x32_bf16(
                        af[mt], bfr, acc[mt][nt], 0, 0, 0);
            }
        }
        __builtin_amdgcn_s_setprio(0);
    }

    // ---- phase A: acc (+bias) -> LDS bf16 tile, swizzled ----
    __syncthreads();
    #pragma unroll
    for (int nt = 0; nt < 5; ++nt) {
        int col = wc * 80 + nt * 16 + l15;
        float bvv = bias0 ? bias0[col] : 0.f;
        #pragma unroll
        for (int mt = 0; mt < 2; ++mt) {
            #pragma unroll
            for (int rr = 0; rr < 4; ++rr) {
                int rowL = wr * 32 + mt * 16 + l4 * 4 + rr;
                *(u16*)(Als + ((rowL * 640 + col * 2) ^ (((rowL >> 2) & 7) << 4)))
                    = f2bf(acc[mt][nt][rr] + bvv);
            }
        }
    }
    __syncthreads();

    // ---- phase B: writer ----
    #pragma unroll
    for (int s = 0; s < 5; ++s) {
        int c = tid + 512 * s;
        int r = c / 40, ch = c - r * 40;
        int grow = rowBase + r;
        if (grow >= M) continue;
        v2u val = *(const v2u*)(Als + ((c * 16) ^ (((r >> 2) & 7) << 4)));
        if (EPI == E_MPG) {
            v2u xv = *(const v2u*)(xepi + (long)grow * PD + ch * 8);
            #pragma unroll
            for (int w = 0; w < 2; ++w) {
                u32 a0 = (u32)val[w], a1 = (u32)(val[w] >> 32);
                u32 x0 = (u32)xv[w],  x1 = (u32)(xv[w] >> 32);
                u32 r0 = cvtpk(fmaxf(lo16(a0) + lo16(x0), 0.f),
                               fmaxf(hi16(a0) + hi16(x0), 0.f));
                u32 r1 = cvtpk(fmaxf(lo16(a1) + lo16(x1), 0.f),
                               fmaxf(hi16(a1) + hi16(x1), 0.f));
                val[w] = (ull)r0 | ((ull)r1 << 32);
            }
        }
        if (OUTM & O_BF16)
            *(v2u*)(Cb0 + (long)grow * PD + ch * 8) = val;
        if (OUTM & O_F32) {
            int col0 = ch * 8;
            if (col0 < DD) {
                u32 a0 = (u32)val[0], a1 = (u32)(val[0] >> 32);
                float4 lo = {lo16(a0), hi16(a0), lo16(a1), hi16(a1)};
                *(float4*)(Cf + (long)grow * DD + col0) = lo;
                if (col0 + 4 < DD) {
                    u32 b0 = (u32)val[1], b1 = (u32)(val[1] >> 32);
                    float4 hi4 = {lo16(b0), hi16(b0), lo16(b1), hi16(b1)};
                    *(float4*)(Cf + (long)grow * DD + col0 + 4) = hi4;
                }
            }
        }
    }
}

// ---- scoreU: s[h,d] = scale*(h_d . G_h[n]); softmax; U_h = sum_d a*h_d ----
__global__ __launch_bounds__(256)
void scoreU_k(const bf16* __restrict__ G0, const bf16* __restrict__ G1,
              const bf16* __restrict__ G2, const bf16* __restrict__ G3,
              const bf16* __restrict__ h, const int* __restrict__ nbr,
              bf16* __restrict__ U0, bf16* __restrict__ U1,
              bf16* __restrict__ U2, bf16* __restrict__ U3)
{
    int wave = threadIdx.x >> 6, lane = threadIdx.x & 63;
    int n = xswz(blockIdx.x, gridDim.x) * 4 + wave;
    if (n >= NN) return;
    int eid[6];
    #pragma unroll
    for (int d = 0; d < 6; ++d) eid[d] = nbr[n * 6 + d];

    bool act = lane < 40;
    int cl = act ? lane : 0;
    long go = (long)n * PD + cl * 8;

    float g[4][8];
    #pragma unroll
    for (int hh = 0; hh < 4; ++hh) {
        const bf16* Gp = (hh == 0) ? G0 : (hh == 1) ? G1 : (hh == 2) ? G2 : G3;
        v2u gv = *(const v2u*)(Gp + go);
        u32 w0 = (u32)gv[0], w1 = (u32)(gv[0] >> 32);
        u32 w2 = (u32)gv[1], w3 = (u32)(gv[1] >> 32);
        g[hh][0] = lo16(w0); g[hh][1] = hi16(w0);
        g[hh][2] = lo16(w1); g[hh][3] = hi16(w1);
        g[hh][4] = lo16(w2); g[hh][5] = hi16(w2);
        g[hh][6] = lo16(w3); g[hh][7] = hi16(w3);
        if (!act)
            #pragma unroll
            for (int i = 0; i < 8; ++i) g[hh][i] = 0.f;
    }
    v2u hp[6];
    #pragma unroll
    for (int d = 0; d < 6; ++d)
        hp[d] = *(const v2u*)(h + (long)eid[d] * PD + cl * 8);

    float s0[6], s1[6], s2[6], s3[6];
    #pragma unroll
    for (int d = 0; d < 6; ++d) {
        u32 w0 = (u32)hp[d][0], w1 = (u32)(hp[d][0] >> 32);
        u32 w2 = (u32)hp[d][1], w3 = (u32)(hp[d][1] >> 32);
        float hf[8] = {lo16(w0), hi16(w0), lo16(w1), hi16(w1),
                       lo16(w2), hi16(w2), lo16(w3), hi16(w3)};
        float p0 = 0, p1 = 0, p2 = 0, p3 = 0;
        #pragma unroll
        for (int i = 0; i < 8; ++i) {
            p0 += g[0][i] * hf[i];
            p1 += g[1][i] * hf[i];
            p2 += g[2][i] * hf[i];
            p3 += g[3][i] * hf[i];
        }
        #pragma unroll
        for (int off = 32; off; off >>= 1) {
            p0 += __shfl_xor(p0, off);
            p1 += __shfl_xor(p1, off);
            p2 += __shfl_xor(p2, off);
            p3 += __shfl_xor(p3, off);
        }
        s0[d] = p0; s1[d] = p1; s2[d] = p2; s3[d] = p3;
    }

    const float scale = 0.1154700538379252f; // 1/sqrt(75)
    float at[4][6];
    {
        float m0 = -1e30f, m1 = -1e30f, m2 = -1e30f, m3 = -1e30f;
        #pragma unroll
        for (int d = 0; d < 6; ++d) {
            s0[d] *= scale; s1[d] *= scale; s2[d] *= scale; s3[d] *= scale;
            m0 = fmaxf(m0, s0[d]); m1 = fmaxf(m1, s1[d]);
            m2 = fmaxf(m2, s2[d]); m3 = fmaxf(m3, s3[d]);
        }
        float t0 = 0, t1 = 0, t2 = 0, t3 = 0;
        #pragma unroll
        for (int d = 0; d < 6; ++d) {
            at[0][d] = expf(s0[d] - m0); t0 += at[0][d];
            at[1][d] = expf(s1[d] - m1); t1 += at[1][d];
            at[2][d] = expf(s2[d] - m2); t2 += at[2][d];
            at[3][d] = expf(s3[d] - m3); t3 += at[3][d];
        }
        t0 = 1.f / t0; t1 = 1.f / t1; t2 = 1.f / t2; t3 = 1.f / t3;
        #pragma unroll
        for (int d = 0; d < 6; ++d) {
            at[0][d] *= t0; at[1][d] *= t1; at[2][d] *= t2; at[3][d] *= t3;
        }
    }

    float u[4][8];
    #pragma unroll
    for (int hh = 0; hh < 4; ++hh)
        #pragma unroll
        for (int i = 0; i < 8; ++i) u[hh][i] = 0.f;
    #pragma unroll
    for (int d = 0; d < 6; ++d) {
        u32 w0 = (u32)hp[d][0], w1 = (u32)(hp[d][0] >> 32);
        u32 w2 = (u32)hp[d][1], w3 = (u32)(hp[d][1] >> 32);
        float hf[8] = {lo16(w0), hi16(w0), lo16(w1), hi16(w1),
                       lo16(w2), hi16(w2), lo16(w3), hi16(w3)};
        #pragma unroll
        for (int i = 0; i < 8; ++i) {
            u[0][i] += at[0][d] * hf[i];
            u[1][i] += at[1][d] * hf[i];
            u[2][i] += at[2][d] * hf[i];
            u[3][i] += at[3][d] * hf[i];
        }
    }
    if (act) {
        #pragma unroll
        for (int hh = 0; hh < 4; ++hh) {
            bf16* Up = (hh == 0) ? U0 : (hh == 1) ? U1 : (hh == 2) ? U2 : U3;
            v2u r;
            r[0] = (ull)cvtpk(u[hh][0], u[hh][1]) |
                   ((ull)cvtpk(u[hh][2], u[hh][3]) << 32);
            r[1] = (ull)cvtpk(u[hh][4], u[hh][5]) |
                   ((ull)cvtpk(u[hh][6], u[hh][7]) << 32);
            *(v2u*)(Up + go) = r;
        }
    }
}

// ---- mail from f32 h_final: mail[n] = sum_d h[nbr[n,d]] -> bf16 padded ----
__global__ __launch_bounds__(256)
void mailf_k(const float* __restrict__ h, const int* __restrict__ nbr,
             bf16* __restrict__ mail)
{
    int idx = xswz(blockIdx.x, gridDim.x) * 256 + threadIdx.x;
    if (idx >= NN * 80) return;
    int n = idx / 80, c4 = idx - n * 80;
    float4 s = {0.f, 0.f, 0.f, 0.f};
    if (c4 < 75) {
        const int* e = nbr + n * 6;
        #pragma unroll
        for (int d = 0; d < 6; ++d) {
            float4 v = *(const float4*)(h + (long)e[d] * DD + c4 * 4);
            s.x += v.x; s.y += v.y; s.z += v.z; s.w += v.w;
        }
    }
    ull r = (ull)cvtpk(s.x, s.y) | ((ull)cvtpk(s.z, s.w) << 32);
    *(ull*)(mail + (long)n * PD + c4 * 4) = r;
}

// ---- f32[rows,300] -> bf16[rows,320] padded ----
__global__ __launch_bounds__(256)
void conv_k(const float* __restrict__ in, bf16* __restrict__ out, int rows)
{
    long idx = (long)blockIdx.x * 256 + threadIdx.x;
    if (idx >= (long)rows * 40) return;
    int r = (int)(idx / 40), ch = (int)(idx - (long)r * 40);
    int c4 = ch * 2;
    float4 a = {0, 0, 0, 0}, b = {0, 0, 0, 0};
    if (c4 < 75)     a = *(const float4*)(in + (long)r * DD + c4 * 4);
    if (c4 + 1 < 75) b = *(const float4*)(in + (long)r * DD + c4 * 4 + 4);
    v2u v;
    v[0] = (ull)cvtpk(a.x, a.y) | ((ull)cvtpk(a.z, a.w) << 32);
    v[1] = (ull)cvtpk(b.x, b.y) | ((ull)cvtpk(b.z, b.w) << 32);
    *(v2u*)(out + (long)r * PD + ch * 8) = v;
}

// ---- weight transpose+convert: BT[c][k] = W[k][c], 320x320 bf16 pad ----
__global__ __launch_bounds__(256)
void tw_k(const float* __restrict__ W, bf16* __restrict__ BT)
{
    int idx = blockIdx.x * 256 + threadIdx.x;
    if (idx >= 320 * 320) return;
    int nn = idx / 320, kk = idx - nn * 320;
    u16 v = 0;
    if (nn < DD && kk < DD) v = f2bf(W[kk * DD + nn]);
    ((u16*)BT)[idx] = v;
}

// ---- f32 transpose: WT[c][r] = W[r][c], [300,300] -> [320,320] pad ----
__global__ __launch_bounds__(256)
void twf_k(const float* __restrict__ W, float* __restrict__ WT)
{
    __shared__ float t[32][33];
    int bx = blockIdx.x % 10, by = blockIdx.x / 10;
    int r0 = by * 32, c0 = bx * 32;
    int tx = threadIdx.x & 31, ty = threadIdx.x >> 5;
    #pragma unroll
    for (int i = 0; i < 4; ++i) {
        int r = r0 + ty + i * 8, c = c0 + tx;
        t[ty + i * 8][tx] = (r < DD && c < DD) ? W[r * DD + c] : 0.f;
    }
    __syncthreads();
    #pragma unroll
    for (int i = 0; i < 4; ++i)
        WT[(c0 + ty + i * 8) * 320 + r0 + tx] = t[tx][ty + i * 8];
}

// ---- composed QK (coalesced): slab[c][k] = sum_j WqT[jb+j][k]*Wk[ci][jb+j] ----
__global__ __launch_bounds__(256)
void wqk_k(const float* __restrict__ WqT, const float* __restrict__ Wk,
           bf16* __restrict__ slab)
{
    int idx = blockIdx.x * 256 + threadIdx.x;
    if (idx >= 1280 * 320) return;
    int c = idx / 320, k = idx - c * 320;
    int hh = c / 320;
    int ci = c - hh * 320;
    float v = 0.f;
    if (ci < DD && k < DD) {
        int jb = hh * 75;
        for (int j = 0; j < 75; ++j)
            v += WqT[(jb + j) * 320 + k] * Wk[ci * DD + jb + j];
    }
    ((u16*)slab)[idx] = f2bf(v);
}

// ---- composed V-O (coalesced): 5 slots: s<4: Wv_h@Wo_h ; s=4: Wv@Wo ----
__global__ __launch_bounds__(256)
void wcomp_k(const float* __restrict__ WvT, const float* __restrict__ Wo,
             bf16* __restrict__ slab)
{
    int idx = blockIdx.x * 256 + threadIdx.x;
    if (idx >= 5 * 320 * 320) return;
    int s = idx / 102400, rem = idx - s * 102400;
    int c = rem / 320, k = rem - c * 320;
    float v = 0.f;
    if (c < DD && k < DD) {
        int jb = (s < 4) ? s * 75 : 0;
        int jn = (s < 4) ? 75 : 300;
        for (int j = 0; j < jn; ++j)
            v += WvT[(jb + j) * 320 + k] * Wo[(jb + j) * DD + c];
    }
    ((u16*)slab)[idx] = f2bf(v);
}

// ---- padded bias vectors (8 x 320 f32) ----
__global__ void bias_k(const float* __restrict__ WkT, const float* __restrict__ Wo,
                       const float* __restrict__ bq, const float* __restrict__ bv,
                       const float* __restrict__ bo, const float* __restrict__ bmp,
                       const float* __restrict__ blast, float* __restrict__ outb)
{
    int a = blockIdx.x, i = threadIdx.x; // 8 x 320
    float v = 0.f;
    if (i < DD) {
        if (a < 4) {
            for (int j = 0; j < 75; ++j)
                v += bq[a * 75 + j] * WkT[(a * 75 + j) * 320 + i];
        } else if (a == 4) {
            for (int j = 0; j < DD; ++j) v += bv[j] * Wo[j * DD + i];
            v += bo[i];
        } else if (a == 5) v = bmp[i];
        else if (a == 6) v = bmp[DD + i];
        else v = blast[i];
    }
    outb[a * 320 + i] = v;
}

extern "C" void kernel_launch(void* const* d_in, const int* in_sizes, int n_in,
                              void* d_out, int out_size, void* d_ws, size_t ws_size,
                              hipStream_t stream)
{
    const float* f     = (const float*)d_in[0];
    const float* x     = (const float*)d_in[1];
    const float* Wq    = (const float*)d_in[2];
    const float* bq    = (const float*)d_in[3];
    const float* Wk    = (const float*)d_in[4];
    const float* bv    = (const float*)d_in[7];
    const float* Wv    = (const float*)d_in[6];
    const float* Wo    = (const float*)d_in[8];
    const float* bo    = (const float*)d_in[9];
    const float* Wmp   = (const float*)d_in[10];
    const float* bmp   = (const float*)d_in[11];
    const float* Wlast = (const float*)d_in[12];
    const float* blast = (const float*)d_in[13];
    const int*   src   = (const int*)d_in[14];
    const int*   nbr   = (const int*)d_in[16];

    float* out     = (float*)d_out;
    float* f_final = out;
    float* h_final = out + (long)NN * DD;

    // ws layout (ends ~772.7 MB; proven-safe bound ~901.8 MB):
    char* ws = (char*)d_ws;
    bf16* xb  = (bf16*)(ws);                   // [E,320] 192e6
    bf16* h1b = (bf16*)(ws + 192000000LL);     // [E,320]
    bf16* fb  = (bf16*)(ws + 576000000LL);     // [N,320] 32e6
    bf16* G0  = (bf16*)(ws + 608000000LL);     // [N,320] x4 (alias U, mail)
    bf16* G1  = (bf16*)(ws + 640000000LL);
    bf16* G2  = (bf16*)(ws + 672000000LL);
    bf16* G3  = (bf16*)(ws + 704000000LL);
    bf16* FHb = (bf16*)(ws + 736000000LL);     // [N,320]
    bf16* WT  = (bf16*)(ws + 768000000LL);     // 14 slots x 204800 B
    float* BIAS = (float*)(ws + 771300000LL);  // 8 x 320 f32
    float* WqT  = (float*)(ws + 771400000LL);  // 320x320 f32 each
    float* WkT  = (float*)(ws + 771850000LL);
    float* WvT  = (float*)(ws + 772300000LL);
    auto slot = [&](int i) { return WT + (long)i * 320 * 320; };
    // slots: 0-3 qk heads | 4-8 fh(comp0..3,vo) | 9 mp0 | 10 mp1 | 11-13 last
    bf16* qk   = slot(0);
    bf16* fh5  = slot(4);
    float* g0p = BIAS;
    float* b2p = BIAS + 1280;
    float* bm0p = BIAS + 1600;  float* bm1p = BIAS + 1920;
    float* blp = BIAS + 2240;
    bf16* MLb = G0;

    dim3 blk(256), blk5(512);
    const int gN = (NN + 63) / 64;   // 782
    const int gE = (EE + 63) / 64;   // 4688

    conv_k<<<(int)(((long)EE * 40 + 255) / 256), blk, 0, stream>>>(x, xb, EE);
    conv_k<<<(int)(((long)NN * 40 + 255) / 256), blk, 0, stream>>>(f, fb, NN);
    twf_k<<<100, blk, 0, stream>>>(Wq, WqT);
    twf_k<<<100, blk, 0, stream>>>(Wk, WkT);
    twf_k<<<100, blk, 0, stream>>>(Wv, WvT);
    wqk_k<<<1600, blk, 0, stream>>>(WqT, Wk, qk);
    wcomp_k<<<2000, blk, 0, stream>>>(WvT, Wo, fh5);
    tw_k<<<400, blk, 0, stream>>>(Wmp, slot(9));
    tw_k<<<400, blk, 0, stream>>>(Wmp + 90000, slot(10));
    tw_k<<<400, blk, 0, stream>>>(Wlast, slot(11));
    tw_k<<<400, blk, 0, stream>>>(Wlast + 90000, slot(12));
    tw_k<<<400, blk, 0, stream>>>(Wlast + 180000, slot(13));
    bias_k<<<8, 320, 0, stream>>>(WkT, Wo, bq, bv, bo, bmp, blast, BIAS);

    for (int it = 0; it < 2; ++it) {
        const bf16* hb  = it ? h1b : xb;
        const bf16* fhb = it ? FHb : fb;
        const bf16* mpW = it ? slot(10) : slot(9);
        // G_h = f_h @ Wqk_h + g_h   (grid.y = 4 heads)
        gemm_mfma<E_BIAS, O_BF16, 1><<<dim3(gN, 4), blk5, 0, stream>>>(
            fhb, nullptr, nullptr, nullptr, nullptr, nullptr,
            qk, g0p, nullptr, nullptr, G0, NN, 16000000);
        // scores + softmax + U_h (U aliases G)
        scoreU_k<<<(NN + 3) / 4, blk, 0, stream>>>(G0, G1, G2, G3, hb, nbr,
                                                   G0, G1, G2, G3);
        // f_h_new = sum_h U_h@Wcomp_h + f_h@Wvo + b2
        gemm_mfma<E_BIAS, O_BF16, 5><<<gN, blk5, 0, stream>>>(
            G0, G1, G2, G3, fhb, nullptr, fh5, b2p, nullptr,
            nullptr, FHb, NN, 0);
        // h_new = relu(x + (f_h[src]-h[rev])@Wmp + bmp)  (register-staged gather)
        if (it == 0) {
            gemm_mfma<E_MPG, O_BF16, 1><<<gE, blk5, 0, stream>>>(
                FHb, hb, nullptr, nullptr, nullptr, src,
                mpW, bm0p, xb, nullptr, h1b, EE, 0);
        } else {
            gemm_mfma<E_MPG, O_F32, 1><<<gE, blk5, 0, stream>>>(
                FHb, hb, nullptr, nullptr, nullptr, src,
                mpW, bm1p, xb, h_final, nullptr, EE, 0);
        }
    }

    mailf_k<<<(NN * 80 + 255) / 256, blk, 0, stream>>>(h_final, nbr, MLb);
    gemm_mfma<E_BIAS, O_F32, 3><<<gN, blk5, 0, stream>>>(
        MLb, FHb, fb, nullptr, nullptr, nullptr, slot(11), blp,
        nullptr, f_final, nullptr, NN, 0);
}